// Round 4
// baseline (475.824 us; speedup 1.0000x reference)
//
#include <hip/hip_runtime.h>
#include <hip/hip_bf16.h>
#include <math.h>

// Problem constants
#define D_MODEL 256
#define DEPTH 2
#define D_INNER 512
#define D_STATE 16
#define D_CONV 4
#define DT_RANK 16
#define BATCH 2
#define SEQLEN 2048
#define MROWS (BATCH * SEQLEN)   // 4096

#define LCH 8     // rows per chunk
#define NCH 512   // total chunks
#define CPB 256   // chunks per batch

typedef __attribute__((ext_vector_type(8))) short bf16x8;
typedef __attribute__((ext_vector_type(4))) float f32x4;

__device__ __forceinline__ float silu(float v) {
    return v / (1.0f + __expf(-v));
}

__device__ __forceinline__ ushort f2bf(float f) {
    union { float f; unsigned u; } v; v.f = f;
    unsigned r = v.u + 0x7FFFu + ((v.u >> 16) & 1u);
    return (ushort)(r >> 16);
}

__device__ __forceinline__ float bf2f(ushort u) {
    union { unsigned u; float f; } v; v.u = ((unsigned)u) << 16;
    return v.f;
}

__device__ __forceinline__ float softplus_f(float x) {
    return (x > 20.f) ? x : __logf(1.f + __expf(x));
}

// Grid-wide barrier: all 512 blocks are co-resident by construction
// (launch_bounds(512,4) => VGPR<=128 => 2 blocks/CU; LDS 57.6KB => 2/CU).
// Epoch-monotonic counter (zeroed in k_cvt each call). Agent-scope
// release/acquire emit the L2 writeback/invalidate needed across XCDs.
__device__ __forceinline__ void gridbar(unsigned* bar, unsigned target) {
    __syncthreads();
    if (threadIdx.x == 0) {
        __threadfence();
        __hip_atomic_fetch_add(bar, 1u, __ATOMIC_RELEASE, __HIP_MEMORY_SCOPE_AGENT);
        while (__hip_atomic_load(bar, __ATOMIC_ACQUIRE, __HIP_MEMORY_SCOPE_AGENT) < target)
            __builtin_amdgcn_s_sleep(2);
    }
    __syncthreads();
}

#define XS_STR 260   // f32 stride, 11-row LN tile
#define HS_STR 264   // ushort stride, bf16 LN output (16 rows, 11 valid)
#define XC_STR 520   // ushort stride, xc/yy LDS tiles

// ---------------------------------------------------------------------------
// k_cvt: f32 -> bf16 tile-major weights + zero the grid barrier counter.
// ---------------------------------------------------------------------------
__global__ __launch_bounds__(256) void k_cvt(
    const float* __restrict__ ipw, const float* __restrict__ xpw,
    const float* __restrict__ opw, ushort* __restrict__ ipwT,
    ushort* __restrict__ xpwT, ushort* __restrict__ opwT,
    unsigned* __restrict__ bar)
{
    size_t tid = (size_t)blockIdx.x * 256 + threadIdx.x;
    if (tid == 0) *bar = 0u;
    {   // ipw: [2][1024 n][256 k] -> per layer [64 nt][8 kt][16 r][32 c]
        int lyr = (int)(tid >> 16), rem = (int)(tid & 65535);
        int n = rem >> 6, k = (rem & 63) * 4;
        float4 v = *(const float4*)(ipw + ((size_t)lyr * 1024 + n) * 256 + k);
        int nt = n >> 4, r = n & 15, kt = k >> 5, c = k & 31;
        ushort4 o = { f2bf(v.x), f2bf(v.y), f2bf(v.z), f2bf(v.w) };
        *(ushort4*)(ipwT + (size_t)lyr * 262144 + (nt * 8 + kt) * 512 + r * 32 + c) = o;
    }
    if (tid < 12288) {   // xpw: [2][48][512] -> per layer [3 nt][16 kt] tiles
        int lyr = (int)(tid / 6144), rem = (int)(tid % 6144);
        int n = rem >> 7, k = (rem & 127) * 4;
        float4 v = *(const float4*)(xpw + ((size_t)lyr * 48 + n) * 512 + k);
        int nt = n >> 4, r = n & 15, kt = k >> 5, c = k & 31;
        ushort4 o = { f2bf(v.x), f2bf(v.y), f2bf(v.z), f2bf(v.w) };
        *(ushort4*)(xpwT + (size_t)lyr * 24576 + (nt * 16 + kt) * 512 + r * 32 + c) = o;
    }
    if (tid < 65536) {   // opw: [2][256][512] -> per layer [16 nt][16 kt]
        int lyr = (int)(tid >> 15), rem = (int)(tid & 32767);
        int n = rem >> 7, k = (rem & 127) * 4;
        float4 v = *(const float4*)(opw + ((size_t)lyr * 256 + n) * 512 + k);
        int nt = n >> 4, r = n & 15, kt = k >> 5, c = k & 31;
        ushort4 o = { f2bf(v.x), f2bf(v.y), f2bf(v.z), f2bf(v.w) };
        *(ushort4*)(opwT + (size_t)lyr * 131072 + (nt * 16 + kt) * 512 + r * 32 + c) = o;
    }
}

// ---------------------------------------------------------------------------
// k_fused: one dispatch per layer. Grid 512 x 512, fully co-resident.
//   Phase A (= front): LN + in_proj + conv + x_proj + local scan summary.
//     z, xc, dbl stay in LDS; only Ssum/sdsum summaries go to global.
//   gridbar -> Phase B (= comb): two-level exclusive prefix over chunks.
//   gridbar -> Phase C (= back): rescan from true h_init (regs a/wdp/bias
//     still live from A), gate, out_proj + residual.
// LDS pool 57664 B with phase overlays (yy over xs+hs; S_l/sd_l over xi_s).
// ---------------------------------------------------------------------------
__global__ __launch_bounds__(512, 4) void k_fused(
    const float* __restrict__ xin, const float* __restrict__ lnwL,
    const float* __restrict__ lnbL, const ushort* __restrict__ ipwT,
    const float* __restrict__ cwL, const float* __restrict__ cbL,
    const ushort* __restrict__ xpwT, const float* __restrict__ dpwL,
    const float* __restrict__ dpbL, const float* __restrict__ alogL,
    const float* __restrict__ dparL, const ushort* __restrict__ opwT,
    float* __restrict__ Ssum, float* __restrict__ sdsum,
    unsigned* __restrict__ bar, unsigned epoch0,
    float* __restrict__ xout)
{
    const int t = threadIdx.x, bid = blockIdx.x;
    const int lane = t & 63, w = t >> 6, l15 = lane & 15, quad = lane >> 4;

    __shared__ __align__(16) char smem[57664];
    float*  xs    = (float*)(smem);            // 11440 B (dead after LN)
    ushort* hs    = (ushort*)(smem + 11456);   //  8448 B (dead after in_proj)
    ushort* yy_s  = (ushort*)(smem);           // 16640 B (phase C, overlays xs+hs)
    ushort* xi_s  = (ushort*)(smem + 19904);   // 11264 B (dead after conv)
    float*  S_l   = (float*)(smem + 19904);    //  2176 B (phase B, overlays xi_s)
    float*  sd_l  = (float*)(smem + 22080);    //  2176 B (phase B)
    ushort* xc_s  = (ushort*)(smem + 31168);   // 16640 B (persists A->C)
    ushort* z_s   = (ushort*)(smem + 47808);   //  8192 B (persists A->C)
    float*  dbl_s = (float*)(smem + 56000);    //  1664 B (persists A->C)

    int m0 = bid * LCH;

    // ================= Phase A =================
    // ---- stage x rows m0-3 .. m0+7 (clamp row<0) ----
    for (int i = t; i < 11 * 64; i += 512) {
        int r = i >> 6, c = (i & 63) * 4;
        int grow = m0 - 3 + r; if (grow < 0) grow = 0;
        float4 v = *(const float4*)(xin + (size_t)grow * D_MODEL + c);
        *(float4*)&xs[r * XS_STR + c] = v;
    }
    __syncthreads();

    // ---- LayerNorm, 11 rows x 16 threads ----
    if (t < 11 * 16) {
        int r = t >> 4, ci = t & 15;
        float s = 0.f, sq = 0.f;
        #pragma unroll
        for (int k = 0; k < 16; k++) {
            float v = xs[r * XS_STR + ci + 16 * k];
            s += v; sq += v * v;
        }
        #pragma unroll
        for (int off = 1; off < 16; off <<= 1) {
            s  += __shfl_xor(s, off, 16);
            sq += __shfl_xor(sq, off, 16);
        }
        float mu  = s * (1.0f / 256.f);
        float var = sq * (1.0f / 256.f) - mu * mu;
        float rst = rsqrtf(var + 1e-5f);
        #pragma unroll
        for (int k = 0; k < 16; k++) {
            int c = ci + 16 * k;
            float v = (xs[r * XS_STR + c] - mu) * rst * lnwL[c] + lnbL[c];
            hs[r * HS_STR + c] = f2bf(v);
        }
    }
    __syncthreads();

    // ---- in_proj MFMA: hoisted af, k-outer / f-inner, tiled weights ----
    {
        bf16x8 af[8];
        #pragma unroll
        for (int k8 = 0; k8 < 8; k8++)
            af[k8] = *(const bf16x8*)&hs[l15 * HS_STR + quad * 8 + k8 * 32];
        f32x4 acc[8];
        #pragma unroll
        for (int f = 0; f < 8; f++) acc[f] = (f32x4){0.f, 0.f, 0.f, 0.f};
        const ushort* wb = ipwT + (size_t)w * 64 * 512 + l15 * 32 + quad * 8;
        #pragma unroll
        for (int k8 = 0; k8 < 8; k8++) {
            #pragma unroll
            for (int f = 0; f < 8; f++) {
                bf16x8 bw = *(const bf16x8*)(wb + (f * 8 + k8) * 512);
                acc[f] = __builtin_amdgcn_mfma_f32_16x16x32_bf16(af[k8], bw, acc[f], 0, 0, 0);
            }
        }
        #pragma unroll
        for (int f = 0; f < 8; f++) {
            int n = w * 128 + f * 16 + l15;
            if (n < 512) {
                #pragma unroll
                for (int r2 = 0; r2 < 4; r2++) {
                    int rl = quad * 4 + r2;
                    if (rl < 11) xi_s[rl * 512 + n] = f2bf(acc[f][r2]);
                }
            } else {
                #pragma unroll
                for (int r2 = 0; r2 < 4; r2++) {
                    int rl = quad * 4 + r2;
                    if (rl >= 3 && rl < 11)
                        z_s[(rl - 3) * 512 + (n - 512)] = f2bf(silu(acc[f][r2]));
                }
            }
        }
    }
    __syncthreads();

    // ---- conv(4) + SiLU -> xc_s (LDS only). d = t ----
    {
        float4 cw4 = *(const float4*)(cwL + t * 4);
        float cbv = cbL[t];
        #pragma unroll
        for (int rl = 0; rl < LCH; rl++) {
            int l = (m0 + rl) & (SEQLEN - 1);
            float s = cbv;
            if (l >= 3) s = fmaf(cw4.x, bf2f(xi_s[(rl + 0) * 512 + t]), s);
            if (l >= 2) s = fmaf(cw4.y, bf2f(xi_s[(rl + 1) * 512 + t]), s);
            if (l >= 1) s = fmaf(cw4.z, bf2f(xi_s[(rl + 2) * 512 + t]), s);
            s = fmaf(cw4.w, bf2f(xi_s[(rl + 3) * 512 + t]), s);
            xc_s[rl * XC_STR + t] = f2bf(silu(s));
        }
    }
    __syncthreads();

    // ---- x_proj MFMA (waves 0..2) -> dbl_s (LDS only) ----
    if (w < 3) {
        const ushort* wb = xpwT + (size_t)w * 16 * 512 + l15 * 32 + quad * 8;
        bf16x8 bw[16];
        #pragma unroll
        for (int k8 = 0; k8 < 16; k8++)
            bw[k8] = *(const bf16x8*)(wb + k8 * 512);
        f32x4 acc = (f32x4){0.f, 0.f, 0.f, 0.f};
        #pragma unroll
        for (int k8 = 0; k8 < 16; k8++) {
            bf16x8 af = *(const bf16x8*)&xc_s[l15 * XC_STR + quad * 8 + k8 * 32];
            acc = __builtin_amdgcn_mfma_f32_16x16x32_bf16(af, bw[k8], acc, 0, 0, 0);
        }
        int n = w * 16 + l15;
        #pragma unroll
        for (int r2 = 0; r2 < 4; r2++) {
            int rl = quad * 4 + r2;
            if (rl < LCH) dbl_s[rl * 52 + n] = acc[r2];
        }
    }
    __syncthreads();

    // ---- local scan summary (d = t), 8 serial steps -> Ssum/sdsum ----
    float a[16], wdp[16], bias, Dd;
    {
        #pragma unroll
        for (int n = 0; n < 16; n++) a[n] = -__expf(alogL[(size_t)t * 16 + n]);
        *(float4*)&wdp[0]  = *(const float4*)(dpwL + (size_t)t * 16 + 0);
        *(float4*)&wdp[4]  = *(const float4*)(dpwL + (size_t)t * 16 + 4);
        *(float4*)&wdp[8]  = *(const float4*)(dpwL + (size_t)t * 16 + 8);
        *(float4*)&wdp[12] = *(const float4*)(dpwL + (size_t)t * 16 + 12);
        bias = dpbL[t];
        Dd = dparL[t];
        float h[16];
        #pragma unroll
        for (int n = 0; n < 16; n++) h[n] = 0.f;
        float sd = 0.f;
        for (int j = 0; j < LCH; j++) {
            const float* dp = &dbl_s[j * 52];
            float d0 = 0.f, d1 = 0.f;
            #pragma unroll
            for (int r2 = 0; r2 < 8; r2++) {
                d0 = fmaf(dp[r2], wdp[r2], d0);
                d1 = fmaf(dp[8 + r2], wdp[8 + r2], d1);
            }
            float dl = softplus_f(bias + d0 + d1);
            float xv = bf2f(xc_s[j * XC_STR + t]);
            float u = dl * xv;
            sd += dl;
            #pragma unroll
            for (int n = 0; n < 16; n++)
                h[n] = fmaf(__expf(dl * a[n]), h[n], dp[16 + n] * u);
        }
        size_t sbase = (size_t)bid * 16 * D_INNER + t;
        #pragma unroll
        for (int n = 0; n < 16; n++) Ssum[sbase + (size_t)n * D_INNER] = h[n];
        sdsum[(size_t)bid * D_INNER + t] = sd;
    }

    // ================= barrier 1 =================
    gridbar(bar, (epoch0 + 1) * NCH);

    // ================= Phase B (comb) =================
    {
        int ch32 = t & 31, seg = t >> 5;
        int chain = bid * 32 + ch32;
        int d = chain & 511;
        int n = (chain >> 9) & 15;
        int b = chain >> 13;
        float ac = -__expf(alogL[(size_t)d * 16 + n]);
        int c0 = b * CPB + seg * 16;

        float s_r[16], sd_r[16];
        float S = 0.f, sdt = 0.f;
        #pragma unroll
        for (int j = 0; j < 16; j++) {
            size_t c = (size_t)(c0 + j);
            float s  = Ssum[(c * 16 + n) * D_INNER + d];
            float sv = sdsum[c * D_INNER + d];
            s_r[j] = s; sd_r[j] = sv;
            S = fmaf(__expf(ac * sv), S, s);
            sdt += sv;
        }
        S_l[ch32 * 17 + seg] = S;
        sd_l[ch32 * 17 + seg] = sdt;
        __syncthreads();

        if (t < 32) {
            float hi = 0.f;
            #pragma unroll
            for (int g = 0; g < 16; g++) {
                float Sv = S_l[t * 17 + g], sdv = sd_l[t * 17 + g];
                S_l[t * 17 + g] = hi;
                hi = fmaf(__expf(ac * sdv), hi, Sv);
            }
        }
        __syncthreads();

        float hi = S_l[ch32 * 17 + seg];
        #pragma unroll
        for (int j = 0; j < 16; j++) {
            size_t c = (size_t)(c0 + j);
            Ssum[(c * 16 + n) * D_INNER + d] = hi;
            hi = fmaf(__expf(ac * sd_r[j]), hi, s_r[j]);
        }
    }

    // ================= barrier 2 =================
    gridbar(bar, (epoch0 + 2) * NCH);

    // ================= Phase C (back) =================
    {
        float h[16];
        size_t sbase = (size_t)bid * 16 * D_INNER + t;
        #pragma unroll
        for (int n = 0; n < 16; n++) h[n] = Ssum[sbase + (size_t)n * D_INNER];
        for (int j = 0; j < LCH; j++) {
            const float* dp = &dbl_s[j * 48 == j * 48 ? j * 52 : 0]; // keep stride 52
            float d0 = 0.f, d1 = 0.f;
            #pragma unroll
            for (int r2 = 0; r2 < 8; r2++) {
                d0 = fmaf(dp[r2], wdp[r2], d0);
                d1 = fmaf(dp[8 + r2], wdp[8 + r2], d1);
            }
            float dl = softplus_f(bias + d0 + d1);
            float xv = bf2f(xc_s[j * XC_STR + t]);
            float gate = bf2f(z_s[j * 512 + t]);
            float u = dl * xv;
            float y0 = 0.f, y1 = 0.f, y2 = 0.f, y3 = 0.f;
            #pragma unroll
            for (int q = 0; q < 4; q++) {
                h[4 * q + 0] = fmaf(__expf(dl * a[4 * q + 0]), h[4 * q + 0], dp[16 + 4 * q + 0] * u);
                h[4 * q + 1] = fmaf(__expf(dl * a[4 * q + 1]), h[4 * q + 1], dp[16 + 4 * q + 1] * u);
                h[4 * q + 2] = fmaf(__expf(dl * a[4 * q + 2]), h[4 * q + 2], dp[16 + 4 * q + 2] * u);
                h[4 * q + 3] = fmaf(__expf(dl * a[4 * q + 3]), h[4 * q + 3], dp[16 + 4 * q + 3] * u);
                y0 = fmaf(h[4 * q + 0], dp[32 + 4 * q + 0], y0);
                y1 = fmaf(h[4 * q + 1], dp[32 + 4 * q + 1], y1);
                y2 = fmaf(h[4 * q + 2], dp[32 + 4 * q + 2], y2);
                y3 = fmaf(h[4 * q + 3], dp[32 + 4 * q + 3], y3);
            }
            float y = (y0 + y1) + (y2 + y3) + xv * Dd;
            yy_s[j * XC_STR + t] = f2bf(y * gate);
        }
    }
    __syncthreads();

    // ---- out_proj MFMA + residual ----
    {
        bf16x8 af[16];
        #pragma unroll
        for (int k8 = 0; k8 < 16; k8++)
            af[k8] = *(const bf16x8*)&yy_s[l15 * XC_STR + quad * 8 + k8 * 32];
        f32x4 acc0 = (f32x4){0.f, 0.f, 0.f, 0.f};
        f32x4 acc1 = (f32x4){0.f, 0.f, 0.f, 0.f};
        const ushort* wb = opwT + (size_t)w * 2 * 16 * 512 + l15 * 32 + quad * 8;
        #pragma unroll
        for (int k8 = 0; k8 < 16; k8++) {
            bf16x8 b0 = *(const bf16x8*)(wb + k8 * 512);
            bf16x8 b1 = *(const bf16x8*)(wb + (16 + k8) * 512);
            acc0 = __builtin_amdgcn_mfma_f32_16x16x32_bf16(af[k8], b0, acc0, 0, 0, 0);
            acc1 = __builtin_amdgcn_mfma_f32_16x16x32_bf16(af[k8], b1, acc1, 0, 0, 0);
        }
        #pragma unroll
        for (int f = 0; f < 2; f++) {
            int n = w * 32 + f * 16 + l15;
            const f32x4& acc = (f == 0) ? acc0 : acc1;
            #pragma unroll
            for (int r2 = 0; r2 < 4; r2++) {
                int rl = quad * 4 + r2;
                if (rl < LCH) {
                    int row = m0 + rl;
                    xout[(size_t)row * D_MODEL + n] =
                        acc[r2] + xin[(size_t)row * D_MODEL + n];
                }
            }
        }
    }
}

// ---------------------------------------------------------------------------
// Launch. Inter-layer activation routed through d_out.
// ---------------------------------------------------------------------------
extern "C" void kernel_launch(void* const* d_in, const int* in_sizes, int n_in,
                              void* d_out, int out_size, void* d_ws, size_t ws_size,
                              hipStream_t stream)
{
    const float* x    = (const float*)d_in[0];
    const float* lnw  = (const float*)d_in[1];
    const float* lnb  = (const float*)d_in[2];
    const float* ipw  = (const float*)d_in[3];
    const float* cw   = (const float*)d_in[4];
    const float* cb   = (const float*)d_in[5];
    const float* xpw  = (const float*)d_in[6];
    const float* dpw  = (const float*)d_in[7];
    const float* dpb  = (const float*)d_in[8];
    const float* alog = (const float*)d_in[9];
    const float* dpar = (const float*)d_in[10];
    const float* opw  = (const float*)d_in[11];
    float* out = (float*)d_out;

    char* p = (char*)d_ws;
    auto alloc = [&](size_t bytes) { char* r = p; p += (bytes + 255) & ~(size_t)255; return r; };
    float*  Ssum  = (float*)alloc((size_t)NCH * 16 * D_INNER * 4);
    float*  sdsum = (float*)alloc((size_t)NCH * D_INNER * 4);
    ushort* ipwT  = (ushort*)alloc((size_t)DEPTH * 262144 * 2);
    ushort* xpwT  = (ushort*)alloc((size_t)DEPTH * 24576 * 2);
    ushort* opwT  = (ushort*)alloc((size_t)DEPTH * 131072 * 2);
    unsigned* bar = (unsigned*)alloc(256);

    k_cvt<<<512, 256, 0, stream>>>(ipw, xpw, opw, ipwT, xpwT, opwT, bar);

    for (int lyr = 0; lyr < DEPTH; lyr++) {
        const float* xin = (lyr == 0) ? x : out;
        float* xout = out;

        k_fused<<<NCH, 512, 0, stream>>>(
            xin, lnw + lyr * D_MODEL, lnb + lyr * D_MODEL,
            ipwT + (size_t)lyr * 262144,
            cw + (size_t)lyr * D_INNER * D_CONV, cb + lyr * D_INNER,
            xpwT + (size_t)lyr * 24576,
            dpw + (size_t)lyr * D_INNER * DT_RANK, dpb + lyr * D_INNER,
            alog + (size_t)lyr * D_INNER * D_STATE, dpar + lyr * D_INNER,
            opwT + (size_t)lyr * 131072,
            Ssum, sdsum, bar, (unsigned)(lyr * 2), xout);
    }
}

// Round 5
// 280.629 us; speedup vs baseline: 1.6956x; 1.6956x over previous
//
#include <hip/hip_runtime.h>
#include <hip/hip_bf16.h>
#include <math.h>

// Problem constants
#define D_MODEL 256
#define DEPTH 2
#define D_INNER 512
#define D_STATE 16
#define D_CONV 4
#define DT_RANK 16
#define BATCH 2
#define SEQLEN 2048
#define MROWS (BATCH * SEQLEN)   // 4096

#define LCH 8     // rows per chunk
#define NCH 512   // total chunks
#define CPB 256   // chunks per batch
#define BAR_FLAGS 64

typedef __attribute__((ext_vector_type(8))) short bf16x8;
typedef __attribute__((ext_vector_type(4))) float f32x4;

__device__ __forceinline__ float silu(float v) {
    return v / (1.0f + __expf(-v));
}

__device__ __forceinline__ ushort f2bf(float f) {
    union { float f; unsigned u; } v; v.f = f;
    unsigned r = v.u + 0x7FFFu + ((v.u >> 16) & 1u);
    return (ushort)(r >> 16);
}

__device__ __forceinline__ float bf2f(ushort u) {
    union { unsigned u; float f; } v; v.u = ((unsigned)u) << 16;
    return v.f;
}

__device__ __forceinline__ float softplus_f(float x) {
    return (x > 20.f) ? x : __logf(1.f + __expf(x));
}

// Grid-wide barrier, cache-neutral spin. All 512 blocks co-resident
// (verified R4: occupancy 47%, kernel completed). Layout of bar[]:
//   bar[0]            monotonic arrival counter
//   bar[32+i*32]      64 broadcast flags, 128B apart (distinct L2 homes)
// Arrival: one RELEASE fetch_add (wbl2 — required for cross-XCD visibility
// of this block's Ssum writes; equivalent to dispatch-boundary cost).
// Wait: relaxed agent-scope RMW on a spread flag — routed to the coherence
// point (correct on non-coherent XCD L2s) but NO cache maintenance, so
// working blocks keep their L1/L2 weight lines (R4's 120us/layer bug).
// One ACQUIRE load after wait (single inv per block per barrier).
__device__ __forceinline__ void gridbar(unsigned* bar, unsigned k) {
    __syncthreads();
    if (threadIdx.x == 0) {
        unsigned old = __hip_atomic_fetch_add(&bar[0], 1u, __ATOMIC_RELEASE,
                                              __HIP_MEMORY_SCOPE_AGENT);
        if (old == k * NCH - 1u) {
            #pragma unroll
            for (int i = 0; i < BAR_FLAGS; i++)
                __hip_atomic_fetch_add(&bar[32 + i * 32], 1u, __ATOMIC_RELAXED,
                                       __HIP_MEMORY_SCOPE_AGENT);
        } else {
            unsigned* f = &bar[32 + (blockIdx.x & (BAR_FLAGS - 1)) * 32];
            while (__hip_atomic_fetch_add(f, 0u, __ATOMIC_RELAXED,
                                          __HIP_MEMORY_SCOPE_AGENT) < k)
                __builtin_amdgcn_s_sleep(8);
        }
        (void)__hip_atomic_load(&bar[0], __ATOMIC_ACQUIRE,
                                __HIP_MEMORY_SCOPE_AGENT);
    }
    __syncthreads();
}

#define XS_STR 260   // f32 stride, 11-row LN tile
#define HS_STR 264   // ushort stride, bf16 LN output (16 rows, 11 valid)
#define XC_STR 520   // ushort stride, xc/yy LDS tiles

// ---------------------------------------------------------------------------
// k_cvt: f32 -> bf16 tile-major weights + zero the barrier state (2080 u32).
// ---------------------------------------------------------------------------
__global__ __launch_bounds__(256) void k_cvt(
    const float* __restrict__ ipw, const float* __restrict__ xpw,
    const float* __restrict__ opw, ushort* __restrict__ ipwT,
    ushort* __restrict__ xpwT, ushort* __restrict__ opwT,
    unsigned* __restrict__ bar)
{
    size_t tid = (size_t)blockIdx.x * 256 + threadIdx.x;
    if (tid < 32 + BAR_FLAGS * 32) bar[tid] = 0u;
    {   // ipw: [2][1024 n][256 k] -> per layer [64 nt][8 kt][16 r][32 c]
        int lyr = (int)(tid >> 16), rem = (int)(tid & 65535);
        int n = rem >> 6, k = (rem & 63) * 4;
        float4 v = *(const float4*)(ipw + ((size_t)lyr * 1024 + n) * 256 + k);
        int nt = n >> 4, r = n & 15, kt = k >> 5, c = k & 31;
        ushort4 o = { f2bf(v.x), f2bf(v.y), f2bf(v.z), f2bf(v.w) };
        *(ushort4*)(ipwT + (size_t)lyr * 262144 + (nt * 8 + kt) * 512 + r * 32 + c) = o;
    }
    if (tid < 12288) {   // xpw: [2][48][512] -> per layer [3 nt][16 kt] tiles
        int lyr = (int)(tid / 6144), rem = (int)(tid % 6144);
        int n = rem >> 7, k = (rem & 127) * 4;
        float4 v = *(const float4*)(xpw + ((size_t)lyr * 48 + n) * 512 + k);
        int nt = n >> 4, r = n & 15, kt = k >> 5, c = k & 31;
        ushort4 o = { f2bf(v.x), f2bf(v.y), f2bf(v.z), f2bf(v.w) };
        *(ushort4*)(xpwT + (size_t)lyr * 24576 + (nt * 16 + kt) * 512 + r * 32 + c) = o;
    }
    if (tid < 65536) {   // opw: [2][256][512] -> per layer [16 nt][16 kt]
        int lyr = (int)(tid >> 15), rem = (int)(tid & 32767);
        int n = rem >> 7, k = (rem & 127) * 4;
        float4 v = *(const float4*)(opw + ((size_t)lyr * 256 + n) * 512 + k);
        int nt = n >> 4, r = n & 15, kt = k >> 5, c = k & 31;
        ushort4 o = { f2bf(v.x), f2bf(v.y), f2bf(v.z), f2bf(v.w) };
        *(ushort4*)(opwT + (size_t)lyr * 131072 + (nt * 16 + kt) * 512 + r * 32 + c) = o;
    }
}

// ---------------------------------------------------------------------------
// k_fused: one dispatch per layer. Grid 512 x 512, fully co-resident.
//   Phase A: LN + in_proj + conv + x_proj + local scan summary (LDS-resident
//            z/xc/dbl; only Ssum/sdsum summaries to global).
//   gridbar -> Phase B: two-level exclusive prefix over chunk summaries.
//   gridbar -> Phase C: rescan from true h_init (a/wdp/bias live in regs
//            from A), gate, out_proj + residual.
// LDS pool 57664 B with phase overlays (yy over xs+hs; S_l/sd_l over xi_s).
// ---------------------------------------------------------------------------
__global__ __launch_bounds__(512, 4) void k_fused(
    const float* __restrict__ xin, const float* __restrict__ lnwL,
    const float* __restrict__ lnbL, const ushort* __restrict__ ipwT,
    const float* __restrict__ cwL, const float* __restrict__ cbL,
    const ushort* __restrict__ xpwT, const float* __restrict__ dpwL,
    const float* __restrict__ dpbL, const float* __restrict__ alogL,
    const float* __restrict__ dparL, const ushort* __restrict__ opwT,
    float* __restrict__ Ssum, float* __restrict__ sdsum,
    unsigned* __restrict__ bar, unsigned epoch0,
    float* __restrict__ xout)
{
    const int t = threadIdx.x, bid = blockIdx.x;
    const int lane = t & 63, w = t >> 6, l15 = lane & 15, quad = lane >> 4;

    __shared__ __align__(16) char smem[57664];
    float*  xs    = (float*)(smem);            // 11440 B (dead after LN)
    ushort* hs    = (ushort*)(smem + 11456);   //  8448 B (dead after in_proj)
    ushort* yy_s  = (ushort*)(smem);           // 16640 B (phase C, overlays xs+hs)
    ushort* xi_s  = (ushort*)(smem + 19904);   // 11264 B (dead after conv)
    float*  S_l   = (float*)(smem + 19904);    //  2176 B (phase B, overlays xi_s)
    float*  sd_l  = (float*)(smem + 22080);    //  2176 B (phase B)
    ushort* xc_s  = (ushort*)(smem + 31168);   // 16640 B (persists A->C)
    ushort* z_s   = (ushort*)(smem + 47808);   //  8192 B (persists A->C)
    float*  dbl_s = (float*)(smem + 56000);    //  1664 B (persists A->C)

    int m0 = bid * LCH;

    // ================= Phase A =================
    // ---- stage x rows m0-3 .. m0+7 (clamp row<0) ----
    for (int i = t; i < 11 * 64; i += 512) {
        int r = i >> 6, c = (i & 63) * 4;
        int grow = m0 - 3 + r; if (grow < 0) grow = 0;
        float4 v = *(const float4*)(xin + (size_t)grow * D_MODEL + c);
        *(float4*)&xs[r * XS_STR + c] = v;
    }
    __syncthreads();

    // ---- LayerNorm, 11 rows x 16 threads ----
    if (t < 11 * 16) {
        int r = t >> 4, ci = t & 15;
        float s = 0.f, sq = 0.f;
        #pragma unroll
        for (int k = 0; k < 16; k++) {
            float v = xs[r * XS_STR + ci + 16 * k];
            s += v; sq += v * v;
        }
        #pragma unroll
        for (int off = 1; off < 16; off <<= 1) {
            s  += __shfl_xor(s, off, 16);
            sq += __shfl_xor(sq, off, 16);
        }
        float mu  = s * (1.0f / 256.f);
        float var = sq * (1.0f / 256.f) - mu * mu;
        float rst = rsqrtf(var + 1e-5f);
        #pragma unroll
        for (int k = 0; k < 16; k++) {
            int c = ci + 16 * k;
            float v = (xs[r * XS_STR + c] - mu) * rst * lnwL[c] + lnbL[c];
            hs[r * HS_STR + c] = f2bf(v);
        }
    }
    __syncthreads();

    // ---- in_proj MFMA: hoisted af, k-outer / f-inner, tiled weights ----
    {
        bf16x8 af[8];
        #pragma unroll
        for (int k8 = 0; k8 < 8; k8++)
            af[k8] = *(const bf16x8*)&hs[l15 * HS_STR + quad * 8 + k8 * 32];
        f32x4 acc[8];
        #pragma unroll
        for (int f = 0; f < 8; f++) acc[f] = (f32x4){0.f, 0.f, 0.f, 0.f};
        const ushort* wb = ipwT + (size_t)w * 64 * 512 + l15 * 32 + quad * 8;
        #pragma unroll
        for (int k8 = 0; k8 < 8; k8++) {
            #pragma unroll
            for (int f = 0; f < 8; f++) {
                bf16x8 bw = *(const bf16x8*)(wb + (f * 8 + k8) * 512);
                acc[f] = __builtin_amdgcn_mfma_f32_16x16x32_bf16(af[k8], bw, acc[f], 0, 0, 0);
            }
        }
        #pragma unroll
        for (int f = 0; f < 8; f++) {
            int n = w * 128 + f * 16 + l15;
            if (n < 512) {
                #pragma unroll
                for (int r2 = 0; r2 < 4; r2++) {
                    int rl = quad * 4 + r2;
                    if (rl < 11) xi_s[rl * 512 + n] = f2bf(acc[f][r2]);
                }
            } else {
                #pragma unroll
                for (int r2 = 0; r2 < 4; r2++) {
                    int rl = quad * 4 + r2;
                    if (rl >= 3 && rl < 11)
                        z_s[(rl - 3) * 512 + (n - 512)] = f2bf(silu(acc[f][r2]));
                }
            }
        }
    }
    __syncthreads();

    // ---- conv(4) + SiLU -> xc_s (LDS only). d = t ----
    {
        float4 cw4 = *(const float4*)(cwL + t * 4);
        float cbv = cbL[t];
        #pragma unroll
        for (int rl = 0; rl < LCH; rl++) {
            int l = (m0 + rl) & (SEQLEN - 1);
            float s = cbv;
            if (l >= 3) s = fmaf(cw4.x, bf2f(xi_s[(rl + 0) * 512 + t]), s);
            if (l >= 2) s = fmaf(cw4.y, bf2f(xi_s[(rl + 1) * 512 + t]), s);
            if (l >= 1) s = fmaf(cw4.z, bf2f(xi_s[(rl + 2) * 512 + t]), s);
            s = fmaf(cw4.w, bf2f(xi_s[(rl + 3) * 512 + t]), s);
            xc_s[rl * XC_STR + t] = f2bf(silu(s));
        }
    }
    __syncthreads();

    // ---- x_proj MFMA (waves 0..2) -> dbl_s (LDS only) ----
    if (w < 3) {
        const ushort* wb = xpwT + (size_t)w * 16 * 512 + l15 * 32 + quad * 8;
        bf16x8 bw[16];
        #pragma unroll
        for (int k8 = 0; k8 < 16; k8++)
            bw[k8] = *(const bf16x8*)(wb + k8 * 512);
        f32x4 acc = (f32x4){0.f, 0.f, 0.f, 0.f};
        #pragma unroll
        for (int k8 = 0; k8 < 16; k8++) {
            bf16x8 af = *(const bf16x8*)&xc_s[l15 * XC_STR + quad * 8 + k8 * 32];
            acc = __builtin_amdgcn_mfma_f32_16x16x32_bf16(af, bw[k8], acc, 0, 0, 0);
        }
        int n = w * 16 + l15;
        #pragma unroll
        for (int r2 = 0; r2 < 4; r2++) {
            int rl = quad * 4 + r2;
            if (rl < LCH) dbl_s[rl * 52 + n] = acc[r2];
        }
    }
    __syncthreads();

    // ---- local scan summary (d = t), 8 serial steps -> Ssum/sdsum ----
    float a[16], wdp[16], bias, Dd;
    {
        #pragma unroll
        for (int n = 0; n < 16; n++) a[n] = -__expf(alogL[(size_t)t * 16 + n]);
        *(float4*)&wdp[0]  = *(const float4*)(dpwL + (size_t)t * 16 + 0);
        *(float4*)&wdp[4]  = *(const float4*)(dpwL + (size_t)t * 16 + 4);
        *(float4*)&wdp[8]  = *(const float4*)(dpwL + (size_t)t * 16 + 8);
        *(float4*)&wdp[12] = *(const float4*)(dpwL + (size_t)t * 16 + 12);
        bias = dpbL[t];
        Dd = dparL[t];
        float h[16];
        #pragma unroll
        for (int n = 0; n < 16; n++) h[n] = 0.f;
        float sd = 0.f;
        for (int j = 0; j < LCH; j++) {
            const float* dp = &dbl_s[j * 52];
            float d0 = 0.f, d1 = 0.f;
            #pragma unroll
            for (int r2 = 0; r2 < 8; r2++) {
                d0 = fmaf(dp[r2], wdp[r2], d0);
                d1 = fmaf(dp[8 + r2], wdp[8 + r2], d1);
            }
            float dl = softplus_f(bias + d0 + d1);
            float xv = bf2f(xc_s[j * XC_STR + t]);
            float u = dl * xv;
            sd += dl;
            #pragma unroll
            for (int n = 0; n < 16; n++)
                h[n] = fmaf(__expf(dl * a[n]), h[n], dp[16 + n] * u);
        }
        size_t sbase = (size_t)bid * 16 * D_INNER + t;
        #pragma unroll
        for (int n = 0; n < 16; n++) Ssum[sbase + (size_t)n * D_INNER] = h[n];
        sdsum[(size_t)bid * D_INNER + t] = sd;
    }

    // ================= barrier 1 =================
    gridbar(bar, epoch0 + 1);

    // ================= Phase B (comb) =================
    {
        int ch32 = t & 31, seg = t >> 5;
        int chain = bid * 32 + ch32;
        int d = chain & 511;
        int n = (chain >> 9) & 15;
        int b = chain >> 13;
        float ac = -__expf(alogL[(size_t)d * 16 + n]);
        int c0 = b * CPB + seg * 16;

        float s_r[16], sd_r[16];
        float S = 0.f, sdt = 0.f;
        #pragma unroll
        for (int j = 0; j < 16; j++) {
            size_t c = (size_t)(c0 + j);
            float s  = Ssum[(c * 16 + n) * D_INNER + d];
            float sv = sdsum[c * D_INNER + d];
            s_r[j] = s; sd_r[j] = sv;
            S = fmaf(__expf(ac * sv), S, s);
            sdt += sv;
        }
        S_l[ch32 * 17 + seg] = S;
        sd_l[ch32 * 17 + seg] = sdt;
        __syncthreads();

        if (t < 32) {
            float hi = 0.f;
            #pragma unroll
            for (int g = 0; g < 16; g++) {
                float Sv = S_l[t * 17 + g], sdv = sd_l[t * 17 + g];
                S_l[t * 17 + g] = hi;
                hi = fmaf(__expf(ac * sdv), hi, Sv);
            }
        }
        __syncthreads();

        float hi = S_l[ch32 * 17 + seg];
        #pragma unroll
        for (int j = 0; j < 16; j++) {
            size_t c = (size_t)(c0 + j);
            Ssum[(c * 16 + n) * D_INNER + d] = hi;
            hi = fmaf(__expf(ac * sd_r[j]), hi, s_r[j]);
        }
    }

    // ================= barrier 2 =================
    gridbar(bar, epoch0 + 2);

    // ================= Phase C (back) =================
    {
        float h[16];
        size_t sbase = (size_t)bid * 16 * D_INNER + t;
        #pragma unroll
        for (int n = 0; n < 16; n++) h[n] = Ssum[sbase + (size_t)n * D_INNER];
        for (int j = 0; j < LCH; j++) {
            const float* dp = &dbl_s[j * 52];
            float d0 = 0.f, d1 = 0.f;
            #pragma unroll
            for (int r2 = 0; r2 < 8; r2++) {
                d0 = fmaf(dp[r2], wdp[r2], d0);
                d1 = fmaf(dp[8 + r2], wdp[8 + r2], d1);
            }
            float dl = softplus_f(bias + d0 + d1);
            float xv = bf2f(xc_s[j * XC_STR + t]);
            float gate = bf2f(z_s[j * 512 + t]);
            float u = dl * xv;
            float y0 = 0.f, y1 = 0.f, y2 = 0.f, y3 = 0.f;
            #pragma unroll
            for (int q = 0; q < 4; q++) {
                h[4 * q + 0] = fmaf(__expf(dl * a[4 * q + 0]), h[4 * q + 0], dp[16 + 4 * q + 0] * u);
                h[4 * q + 1] = fmaf(__expf(dl * a[4 * q + 1]), h[4 * q + 1], dp[16 + 4 * q + 1] * u);
                h[4 * q + 2] = fmaf(__expf(dl * a[4 * q + 2]), h[4 * q + 2], dp[16 + 4 * q + 2] * u);
                h[4 * q + 3] = fmaf(__expf(dl * a[4 * q + 3]), h[4 * q + 3], dp[16 + 4 * q + 3] * u);
                y0 = fmaf(h[4 * q + 0], dp[32 + 4 * q + 0], y0);
                y1 = fmaf(h[4 * q + 1], dp[32 + 4 * q + 1], y1);
                y2 = fmaf(h[4 * q + 2], dp[32 + 4 * q + 2], y2);
                y3 = fmaf(h[4 * q + 3], dp[32 + 4 * q + 3], y3);
            }
            float y = (y0 + y1) + (y2 + y3) + xv * Dd;
            yy_s[j * XC_STR + t] = f2bf(y * gate);
        }
    }
    __syncthreads();

    // ---- out_proj MFMA + residual ----
    {
        bf16x8 af[16];
        #pragma unroll
        for (int k8 = 0; k8 < 16; k8++)
            af[k8] = *(const bf16x8*)&yy_s[l15 * XC_STR + quad * 8 + k8 * 32];
        f32x4 acc0 = (f32x4){0.f, 0.f, 0.f, 0.f};
        f32x4 acc1 = (f32x4){0.f, 0.f, 0.f, 0.f};
        const ushort* wb = opwT + (size_t)w * 2 * 16 * 512 + l15 * 32 + quad * 8;
        #pragma unroll
        for (int k8 = 0; k8 < 16; k8++) {
            bf16x8 b0 = *(const bf16x8*)(wb + k8 * 512);
            bf16x8 b1 = *(const bf16x8*)(wb + (16 + k8) * 512);
            acc0 = __builtin_amdgcn_mfma_f32_16x16x32_bf16(af[k8], b0, acc0, 0, 0, 0);
            acc1 = __builtin_amdgcn_mfma_f32_16x16x32_bf16(af[k8], b1, acc1, 0, 0, 0);
        }
        #pragma unroll
        for (int f = 0; f < 2; f++) {
            int n = w * 32 + f * 16 + l15;
            const f32x4& acc = (f == 0) ? acc0 : acc1;
            #pragma unroll
            for (int r2 = 0; r2 < 4; r2++) {
                int rl = quad * 4 + r2;
                if (rl < LCH) {
                    int row = m0 + rl;
                    xout[(size_t)row * D_MODEL + n] =
                        acc[r2] + xin[(size_t)row * D_MODEL + n];
                }
            }
        }
    }
}

// ---------------------------------------------------------------------------
// Launch. Inter-layer activation routed through d_out.
// ---------------------------------------------------------------------------
extern "C" void kernel_launch(void* const* d_in, const int* in_sizes, int n_in,
                              void* d_out, int out_size, void* d_ws, size_t ws_size,
                              hipStream_t stream)
{
    const float* x    = (const float*)d_in[0];
    const float* lnw  = (const float*)d_in[1];
    const float* lnb  = (const float*)d_in[2];
    const float* ipw  = (const float*)d_in[3];
    const float* cw   = (const float*)d_in[4];
    const float* cb   = (const float*)d_in[5];
    const float* xpw  = (const float*)d_in[6];
    const float* dpw  = (const float*)d_in[7];
    const float* dpb  = (const float*)d_in[8];
    const float* alog = (const float*)d_in[9];
    const float* dpar = (const float*)d_in[10];
    const float* opw  = (const float*)d_in[11];
    float* out = (float*)d_out;

    char* p = (char*)d_ws;
    auto alloc = [&](size_t bytes) { char* r = p; p += (bytes + 255) & ~(size_t)255; return r; };
    float*  Ssum  = (float*)alloc((size_t)NCH * 16 * D_INNER * 4);
    float*  sdsum = (float*)alloc((size_t)NCH * D_INNER * 4);
    ushort* ipwT  = (ushort*)alloc((size_t)DEPTH * 262144 * 2);
    ushort* xpwT  = (ushort*)alloc((size_t)DEPTH * 24576 * 2);
    ushort* opwT  = (ushort*)alloc((size_t)DEPTH * 131072 * 2);
    unsigned* bar = (unsigned*)alloc((32 + BAR_FLAGS * 32) * 4);

    k_cvt<<<512, 256, 0, stream>>>(ipw, xpw, opw, ipwT, xpwT, opwT, bar);

    for (int lyr = 0; lyr < DEPTH; lyr++) {
        const float* xin = (lyr == 0) ? x : out;
        float* xout = out;

        k_fused<<<NCH, 512, 0, stream>>>(
            xin, lnw + lyr * D_MODEL, lnb + lyr * D_MODEL,
            ipwT + (size_t)lyr * 262144,
            cw + (size_t)lyr * D_INNER * D_CONV, cb + lyr * D_INNER,
            xpwT + (size_t)lyr * 24576,
            dpw + (size_t)lyr * D_INNER * DT_RANK, dpb + lyr * D_INNER,
            alog + (size_t)lyr * D_INNER * D_STATE, dpar + lyr * D_INNER,
            opwT + (size_t)lyr * 131072,
            Ssum, sdsum, bar, (unsigned)(lyr * 2), xout);
    }
}

// Round 6
// 204.857 us; speedup vs baseline: 2.3227x; 1.3699x over previous
//
#include <hip/hip_runtime.h>
#include <hip/hip_bf16.h>
#include <math.h>

// Problem constants
#define D_MODEL 256
#define DEPTH 2
#define D_INNER 512
#define D_STATE 16
#define D_CONV 4
#define DT_RANK 16
#define BATCH 2
#define SEQLEN 2048
#define MROWS (BATCH * SEQLEN)   // 4096

#define LCH 8     // rows per chunk
#define NCH 512   // total chunks
#define CPB 256   // chunks per batch

typedef __attribute__((ext_vector_type(8))) short bf16x8;
typedef __attribute__((ext_vector_type(4))) float f32x4;

__device__ __forceinline__ float silu(float v) {
    return v / (1.0f + __expf(-v));
}

__device__ __forceinline__ ushort f2bf(float f) {
    union { float f; unsigned u; } v; v.f = f;
    unsigned r = v.u + 0x7FFFu + ((v.u >> 16) & 1u);
    return (ushort)(r >> 16);
}

__device__ __forceinline__ float bf2f(ushort u) {
    union { unsigned u; float f; } v; v.u = ((unsigned)u) << 16;
    return v.f;
}

__device__ __forceinline__ float softplus_f(float x) {
    return (x > 20.f) ? x : __logf(1.f + __expf(x));
}

#define XS_STR 260   // f32 stride, 11-row LN tile
#define HS_STR 264   // ushort stride, bf16 LN output (16 rows, 11 valid)
#define XC_STR 520   // ushort stride, xc/yy LDS tiles

// ---------------------------------------------------------------------------
// k_cvt: f32 -> bf16 AND re-layout to MFMA tile-major: per (nt,kt) a 1-KB
// tile [16 r][32 c] so one wave weight-load = one coalesced 1-KB segment.
// ---------------------------------------------------------------------------
__global__ __launch_bounds__(256) void k_cvt(
    const float* __restrict__ ipw, const float* __restrict__ xpw,
    const float* __restrict__ opw, ushort* __restrict__ ipwT,
    ushort* __restrict__ xpwT, ushort* __restrict__ opwT)
{
    size_t tid = (size_t)blockIdx.x * 256 + threadIdx.x;
    {   // ipw: [2][1024 n][256 k] -> per layer [64 nt][8 kt][16 r][32 c]
        int lyr = (int)(tid >> 16), rem = (int)(tid & 65535);
        int n = rem >> 6, k = (rem & 63) * 4;
        float4 v = *(const float4*)(ipw + ((size_t)lyr * 1024 + n) * 256 + k);
        int nt = n >> 4, r = n & 15, kt = k >> 5, c = k & 31;
        ushort4 o = { f2bf(v.x), f2bf(v.y), f2bf(v.z), f2bf(v.w) };
        *(ushort4*)(ipwT + (size_t)lyr * 262144 + (nt * 8 + kt) * 512 + r * 32 + c) = o;
    }
    if (tid < 12288) {   // xpw: [2][48][512] -> per layer [3 nt][16 kt] tiles
        int lyr = (int)(tid / 6144), rem = (int)(tid % 6144);
        int n = rem >> 7, k = (rem & 127) * 4;
        float4 v = *(const float4*)(xpw + ((size_t)lyr * 48 + n) * 512 + k);
        int nt = n >> 4, r = n & 15, kt = k >> 5, c = k & 31;
        ushort4 o = { f2bf(v.x), f2bf(v.y), f2bf(v.z), f2bf(v.w) };
        *(ushort4*)(xpwT + (size_t)lyr * 24576 + (nt * 16 + kt) * 512 + r * 32 + c) = o;
    }
    if (tid < 65536) {   // opw: [2][256][512] -> per layer [16 nt][16 kt]
        int lyr = (int)(tid >> 15), rem = (int)(tid & 32767);
        int n = rem >> 7, k = (rem & 127) * 4;
        float4 v = *(const float4*)(opw + ((size_t)lyr * 256 + n) * 512 + k);
        int nt = n >> 4, r = n & 15, kt = k >> 5, c = k & 31;
        ushort4 o = { f2bf(v.x), f2bf(v.y), f2bf(v.z), f2bf(v.w) };
        *(ushort4*)(opwT + (size_t)lyr * 131072 + (nt * 16 + kt) * 512 + r * 32 + c) = o;
    }
}

// ---------------------------------------------------------------------------
// k_front: 8-row chunk. LN (11 rows, 32 thr/row) + in_proj MFMA (tiled
// weights, explicit 2-deep weight double-buffer, f split 4+4) + conv +
// x_proj + scan_sum. Grid 512 x 512, 2 blocks/CU.
// ---------------------------------------------------------------------------
__global__ __launch_bounds__(512, 4) void k_front(
    const float* __restrict__ xin, const float* __restrict__ lnwL,
    const float* __restrict__ lnbL, const ushort* __restrict__ ipwT,
    const float* __restrict__ cwL, const float* __restrict__ cbL,
    const ushort* __restrict__ xpwT, const float* __restrict__ dpwL,
    const float* __restrict__ dpbL, const float* __restrict__ alogL,
    ushort* __restrict__ zsB, ushort* __restrict__ xcB,
    float* __restrict__ dbl, float* __restrict__ Ssum,
    float* __restrict__ sdsum)
{
    const int t = threadIdx.x, bid = blockIdx.x;
    const int lane = t & 63, w = t >> 6, l15 = lane & 15, quad = lane >> 4;
    __shared__ float  xs[11 * XS_STR];     // 11.4 KB
    __shared__ ushort hs[16 * HS_STR];     //  8.4 KB (rows 11-15 garbage)
    __shared__ ushort xi_s[11 * 512];      // 11.3 KB  rows: m0-3 .. m0+7
    __shared__ ushort xc_s[16 * XC_STR];   // 16.6 KB (rows 8-15 garbage)
    __shared__ float  dbl_s[8 * 52];       //  1.7 KB
    int m0 = bid * LCH;

    // ---- stage x rows m0-3 .. m0+7 (clamp row<0) ----
    for (int i = t; i < 11 * 64; i += 512) {
        int r = i >> 6, c = (i & 63) * 4;
        int grow = m0 - 3 + r; if (grow < 0) grow = 0;
        float4 v = *(const float4*)(xin + (size_t)grow * D_MODEL + c);
        *(float4*)&xs[r * XS_STR + c] = v;
    }
    __syncthreads();

    // ---- LayerNorm, 11 rows x 32 threads ----
    if (t < 11 * 32) {
        int r = t >> 5, ci = t & 31;
        float s = 0.f, sq = 0.f;
        #pragma unroll
        for (int k = 0; k < 8; k++) {
            float v = xs[r * XS_STR + ci + 32 * k];
            s += v; sq += v * v;
        }
        #pragma unroll
        for (int off = 1; off < 32; off <<= 1) {
            s  += __shfl_xor(s, off, 32);
            sq += __shfl_xor(sq, off, 32);
        }
        float mu  = s * (1.0f / 256.f);
        float var = sq * (1.0f / 256.f) - mu * mu;
        float rst = rsqrtf(var + 1e-5f);
        #pragma unroll
        for (int k = 0; k < 8; k++) {
            int c = ci + 32 * k;
            float v = (xs[r * XS_STR + c] - mu) * rst * lnwL[c] + lnbL[c];
            hs[r * HS_STR + c] = f2bf(v);
        }
    }
    __syncthreads();

    // ---- in_proj MFMA: f split 4+4, 2-deep weight double-buffer ----
    {
        bf16x8 af[8];
        #pragma unroll
        for (int k8 = 0; k8 < 8; k8++)
            af[k8] = *(const bf16x8*)&hs[l15 * HS_STR + quad * 8 + k8 * 32];
        const ushort* wb = ipwT + (size_t)w * 64 * 512 + l15 * 32 + quad * 8;

        #pragma unroll
        for (int half = 0; half < 2; half++) {
            const ushort* wh = wb + (size_t)half * 4 * 8 * 512;
            f32x4 acc[4];
            #pragma unroll
            for (int f = 0; f < 4; f++) acc[f] = (f32x4){0.f, 0.f, 0.f, 0.f};
            bf16x8 bA[4], bB[4];
            #pragma unroll
            for (int f = 0; f < 4; f++) bA[f] = *(const bf16x8*)(wh + (f * 8) * 512);
            #pragma unroll
            for (int k8 = 0; k8 < 8; k8++) {
                bf16x8* cur = (k8 & 1) ? bB : bA;   // compile-time after unroll
                bf16x8* nxt = (k8 & 1) ? bA : bB;
                if (k8 < 7) {
                    #pragma unroll
                    for (int f = 0; f < 4; f++)
                        nxt[f] = *(const bf16x8*)(wh + (f * 8 + k8 + 1) * 512);
                }
                #pragma unroll
                for (int f = 0; f < 4; f++)
                    acc[f] = __builtin_amdgcn_mfma_f32_16x16x32_bf16(af[k8], cur[f], acc[f], 0, 0, 0);
            }
            #pragma unroll
            for (int f = 0; f < 4; f++) {
                int n = w * 128 + (half * 4 + f) * 16 + l15;
                if (n < 512) {
                    #pragma unroll
                    for (int r2 = 0; r2 < 4; r2++) {
                        int rl = quad * 4 + r2;
                        if (rl < 11) xi_s[rl * 512 + n] = f2bf(acc[f][r2]);
                    }
                } else {
                    #pragma unroll
                    for (int r2 = 0; r2 < 4; r2++) {
                        int rl = quad * 4 + r2;
                        if (rl >= 3 && rl < 11)
                            zsB[(size_t)(m0 + rl - 3) * D_INNER + (n - 512)] =
                                f2bf(silu(acc[f][r2]));
                    }
                }
            }
        }
    }
    __syncthreads();

    // ---- conv(4) + SiLU -> xc_s + xcB. d = t, all 512 threads ----
    {
        float4 cw4 = *(const float4*)(cwL + t * 4);
        float cbv = cbL[t];
        #pragma unroll
        for (int rl = 0; rl < LCH; rl++) {
            int l = (m0 + rl) & (SEQLEN - 1);
            float s = cbv;
            if (l >= 3) s = fmaf(cw4.x, bf2f(xi_s[(rl + 0) * 512 + t]), s);
            if (l >= 2) s = fmaf(cw4.y, bf2f(xi_s[(rl + 1) * 512 + t]), s);
            if (l >= 1) s = fmaf(cw4.z, bf2f(xi_s[(rl + 2) * 512 + t]), s);
            s = fmaf(cw4.w, bf2f(xi_s[(rl + 3) * 512 + t]), s);
            ushort xcv = f2bf(silu(s));
            xc_s[rl * XC_STR + t] = xcv;
            xcB[(size_t)(m0 + rl) * D_INNER + t] = xcv;
        }
    }
    __syncthreads();

    // ---- x_proj MFMA (waves 0..2): prefetch all 16 bw, then MFMA chain ----
    if (w < 3) {
        const ushort* wb = xpwT + (size_t)w * 16 * 512 + l15 * 32 + quad * 8;
        bf16x8 bw[16];
        #pragma unroll
        for (int k8 = 0; k8 < 16; k8++)
            bw[k8] = *(const bf16x8*)(wb + k8 * 512);
        f32x4 acc = (f32x4){0.f, 0.f, 0.f, 0.f};
        #pragma unroll
        for (int k8 = 0; k8 < 16; k8++) {
            bf16x8 af = *(const bf16x8*)&xc_s[l15 * XC_STR + quad * 8 + k8 * 32];
            acc = __builtin_amdgcn_mfma_f32_16x16x32_bf16(af, bw[k8], acc, 0, 0, 0);
        }
        int n = w * 16 + l15;
        #pragma unroll
        for (int r2 = 0; r2 < 4; r2++) {
            int rl = quad * 4 + r2;
            if (rl < LCH) {
                dbl_s[rl * 52 + n] = acc[r2];
                dbl[(size_t)(m0 + rl) * 48 + n] = acc[r2];
            }
        }
    }
    __syncthreads();

    // ---- scan_sum (d = t, all 512 threads), 8 serial steps ----
    {
        float a[16], wdp[16];
        #pragma unroll
        for (int n = 0; n < 16; n++) a[n] = -__expf(alogL[(size_t)t * 16 + n]);
        *(float4*)&wdp[0]  = *(const float4*)(dpwL + (size_t)t * 16 + 0);
        *(float4*)&wdp[4]  = *(const float4*)(dpwL + (size_t)t * 16 + 4);
        *(float4*)&wdp[8]  = *(const float4*)(dpwL + (size_t)t * 16 + 8);
        *(float4*)&wdp[12] = *(const float4*)(dpwL + (size_t)t * 16 + 12);
        float bias = dpbL[t];
        float h[16];
        #pragma unroll
        for (int n = 0; n < 16; n++) h[n] = 0.f;
        float sd = 0.f;
        for (int j = 0; j < LCH; j++) {
            const float* dp = &dbl_s[j * 52];
            float d0 = 0.f, d1 = 0.f;
            #pragma unroll
            for (int r2 = 0; r2 < 8; r2++) {
                d0 = fmaf(dp[r2], wdp[r2], d0);
                d1 = fmaf(dp[8 + r2], wdp[8 + r2], d1);
            }
            float dl = softplus_f(bias + d0 + d1);
            float xv = bf2f(xc_s[j * XC_STR + t]);
            float u = dl * xv;
            sd += dl;
            #pragma unroll
            for (int n = 0; n < 16; n++)
                h[n] = fmaf(__expf(dl * a[n]), h[n], dp[16 + n] * u);
        }
        size_t sbase = (size_t)bid * 16 * D_INNER + t;
        #pragma unroll
        for (int n = 0; n < 16; n++) Ssum[sbase + (size_t)n * D_INNER] = h[n];
        sdsum[(size_t)bid * D_INNER + t] = sd;
    }
}

// ---------------------------------------------------------------------------
// k_comb: two-level exclusive prefix over 512 chunk summaries. Grid 512x512.
// ---------------------------------------------------------------------------
__global__ __launch_bounds__(512, 4) void k_comb(
    const float* __restrict__ alogL, const float* __restrict__ sdsum,
    float* __restrict__ Ssum)
{
    const int t = threadIdx.x, bid = blockIdx.x;
    __shared__ float S_l[32][17], sd_l[32][17];
    int ch32 = t & 31, seg = t >> 5;
    int chain = bid * 32 + ch32;
    int d = chain & 511;
    int n = (chain >> 9) & 15;
    int b = chain >> 13;
    float a = -__expf(alogL[(size_t)d * 16 + n]);
    int c0 = b * CPB + seg * 16;

    float s_r[16], sd_r[16];
    float S = 0.f, sdt = 0.f;
    #pragma unroll
    for (int j = 0; j < 16; j++) {
        size_t c = (size_t)(c0 + j);
        float s  = Ssum[(c * 16 + n) * D_INNER + d];
        float sd = sdsum[c * D_INNER + d];
        s_r[j] = s; sd_r[j] = sd;
        S = fmaf(__expf(a * sd), S, s);
        sdt += sd;
    }
    S_l[ch32][seg] = S;
    sd_l[ch32][seg] = sdt;
    __syncthreads();

    if (t < 32) {
        float hi = 0.f;
        #pragma unroll
        for (int g = 0; g < 16; g++) {
            float Sv = S_l[t][g], sdv = sd_l[t][g];
            S_l[t][g] = hi;
            hi = fmaf(__expf(a * sdv), hi, Sv);
        }
    }
    __syncthreads();

    float hi = S_l[ch32][seg];
    #pragma unroll
    for (int j = 0; j < 16; j++) {
        size_t c = (size_t)(c0 + j);
        Ssum[(c * 16 + n) * D_INNER + d] = hi;
        hi = fmaf(__expf(a * sd_r[j]), hi, s_r[j]);
    }
}

// ---------------------------------------------------------------------------
// k_back: 8-row chunk. dbl staged to LDS; rescan from true h_init + D-skip +
// SiLU(z) gate; out_proj MFMA (per-k8 LDS af + 2-deep weight ping-pong) +
// residual. Grid 512 x 512, 2 blocks/CU.
// ---------------------------------------------------------------------------
__global__ __launch_bounds__(512, 4) void k_back(
    const float* __restrict__ dbl, const ushort* __restrict__ xcB,
    const ushort* __restrict__ zsB, const float* __restrict__ Ssum,
    const float* __restrict__ dpwL, const float* __restrict__ dpbL,
    const float* __restrict__ alogL, const float* __restrict__ dparL,
    const ushort* __restrict__ opwT, const float* __restrict__ xin,
    float* __restrict__ xout)
{
    const int t = threadIdx.x, bid = blockIdx.x;
    const int lane = t & 63, w = t >> 6, l15 = lane & 15, quad = lane >> 4;
    __shared__ ushort yy_s[16 * XC_STR];   // 16.6 KB (rows 8-15 garbage)
    __shared__ float  dbl_l[8 * 48];       //  1.5 KB
    int m0 = bid * LCH;

    // ---- stage this chunk's dbl rows (block-uniform data) into LDS ----
    if (t < 8 * 48) dbl_l[t] = dbl[(size_t)m0 * 48 + t];
    __syncthreads();

    // ---- rescan, d = t ----
    {
        float a[16], wdp[16];
        #pragma unroll
        for (int n = 0; n < 16; n++) a[n] = -__expf(alogL[(size_t)t * 16 + n]);
        *(float4*)&wdp[0]  = *(const float4*)(dpwL + (size_t)t * 16 + 0);
        *(float4*)&wdp[4]  = *(const float4*)(dpwL + (size_t)t * 16 + 4);
        *(float4*)&wdp[8]  = *(const float4*)(dpwL + (size_t)t * 16 + 8);
        *(float4*)&wdp[12] = *(const float4*)(dpwL + (size_t)t * 16 + 12);
        float bias = dpbL[t];
        float Dd = dparL[t];
        float h[16];
        size_t sbase = (size_t)bid * 16 * D_INNER + t;
        #pragma unroll
        for (int n = 0; n < 16; n++) h[n] = Ssum[sbase + (size_t)n * D_INNER];
        for (int j = 0; j < LCH; j++) {
            int row = m0 + j;
            const float* dp = &dbl_l[j * 48];
            float d0 = 0.f, d1 = 0.f;
            #pragma unroll
            for (int r2 = 0; r2 < 8; r2++) {
                d0 = fmaf(dp[r2], wdp[r2], d0);
                d1 = fmaf(dp[8 + r2], wdp[8 + r2], d1);
            }
            float dl = softplus_f(bias + d0 + d1);
            float xv = bf2f(xcB[(size_t)row * D_INNER + t]);
            float gate = bf2f(zsB[(size_t)row * D_INNER + t]);
            float u = dl * xv;
            float y0 = 0.f, y1 = 0.f, y2 = 0.f, y3 = 0.f;
            #pragma unroll
            for (int q = 0; q < 4; q++) {
                h[4 * q + 0] = fmaf(__expf(dl * a[4 * q + 0]), h[4 * q + 0], dp[16 + 4 * q + 0] * u);
                h[4 * q + 1] = fmaf(__expf(dl * a[4 * q + 1]), h[4 * q + 1], dp[16 + 4 * q + 1] * u);
                h[4 * q + 2] = fmaf(__expf(dl * a[4 * q + 2]), h[4 * q + 2], dp[16 + 4 * q + 2] * u);
                h[4 * q + 3] = fmaf(__expf(dl * a[4 * q + 3]), h[4 * q + 3], dp[16 + 4 * q + 3] * u);
                y0 = fmaf(h[4 * q + 0], dp[32 + 4 * q + 0], y0);
                y1 = fmaf(h[4 * q + 1], dp[32 + 4 * q + 1], y1);
                y2 = fmaf(h[4 * q + 2], dp[32 + 4 * q + 2], y2);
                y3 = fmaf(h[4 * q + 3], dp[32 + 4 * q + 3], y3);
            }
            float y = (y0 + y1) + (y2 + y3) + xv * Dd;
            yy_s[j * XC_STR + t] = f2bf(y * gate);
        }
    }
    __syncthreads();

    // ---- out_proj MFMA + residual: per-k8 LDS af, 2-deep weight ping-pong --
    {
        const ushort* wb = opwT + (size_t)w * 2 * 16 * 512 + l15 * 32 + quad * 8;
        f32x4 acc0 = (f32x4){0.f, 0.f, 0.f, 0.f};
        f32x4 acc1 = (f32x4){0.f, 0.f, 0.f, 0.f};
        bf16x8 bA0 = *(const bf16x8*)(wb + 0 * 512);
        bf16x8 bA1 = *(const bf16x8*)(wb + 16 * 512);
        bf16x8 bB0, bB1;
        #pragma unroll
        for (int k8 = 0; k8 < 16; k8++) {
            if (k8 < 15) {
                if (k8 & 1) { bA0 = *(const bf16x8*)(wb + (k8 + 1) * 512);
                              bA1 = *(const bf16x8*)(wb + (16 + k8 + 1) * 512); }
                else        { bB0 = *(const bf16x8*)(wb + (k8 + 1) * 512);
                              bB1 = *(const bf16x8*)(wb + (16 + k8 + 1) * 512); }
            }
            bf16x8 af = *(const bf16x8*)&yy_s[l15 * XC_STR + quad * 8 + k8 * 32];
            bf16x8 c0 = (k8 & 1) ? bB0 : bA0;
            bf16x8 c1 = (k8 & 1) ? bB1 : bA1;
            acc0 = __builtin_amdgcn_mfma_f32_16x16x32_bf16(af, c0, acc0, 0, 0, 0);
            acc1 = __builtin_amdgcn_mfma_f32_16x16x32_bf16(af, c1, acc1, 0, 0, 0);
        }
        #pragma unroll
        for (int f = 0; f < 2; f++) {
            int n = w * 32 + f * 16 + l15;
            const f32x4& acc = (f == 0) ? acc0 : acc1;
            #pragma unroll
            for (int r2 = 0; r2 < 4; r2++) {
                int rl = quad * 4 + r2;
                if (rl < LCH) {
                    int row = m0 + rl;
                    xout[(size_t)row * D_MODEL + n] =
                        acc[r2] + xin[(size_t)row * D_MODEL + n];
                }
            }
        }
    }
}

// ---------------------------------------------------------------------------
// Launch. Inter-layer activation routed through d_out.
// ---------------------------------------------------------------------------
extern "C" void kernel_launch(void* const* d_in, const int* in_sizes, int n_in,
                              void* d_out, int out_size, void* d_ws, size_t ws_size,
                              hipStream_t stream)
{
    const float* x    = (const float*)d_in[0];
    const float* lnw  = (const float*)d_in[1];
    const float* lnb  = (const float*)d_in[2];
    const float* ipw  = (const float*)d_in[3];
    const float* cw   = (const float*)d_in[4];
    const float* cb   = (const float*)d_in[5];
    const float* xpw  = (const float*)d_in[6];
    const float* dpw  = (const float*)d_in[7];
    const float* dpb  = (const float*)d_in[8];
    const float* alog = (const float*)d_in[9];
    const float* dpar = (const float*)d_in[10];
    const float* opw  = (const float*)d_in[11];
    float* out = (float*)d_out;

    char* p = (char*)d_ws;
    auto alloc = [&](size_t bytes) { char* r = p; p += (bytes + 255) & ~(size_t)255; return r; };
    ushort* zsB   = (ushort*)alloc((size_t)MROWS * D_INNER * 2);
    ushort* xcB   = (ushort*)alloc((size_t)MROWS * D_INNER * 2);
    float*  dbl   = (float*)alloc((size_t)MROWS * 48 * 4);
    float*  Ssum  = (float*)alloc((size_t)NCH * 16 * D_INNER * 4);
    float*  sdsum = (float*)alloc((size_t)NCH * D_INNER * 4);
    ushort* ipwT  = (ushort*)alloc((size_t)DEPTH * 262144 * 2);
    ushort* xpwT  = (ushort*)alloc((size_t)DEPTH * 24576 * 2);
    ushort* opwT  = (ushort*)alloc((size_t)DEPTH * 131072 * 2);

    k_cvt<<<512, 256, 0, stream>>>(ipw, xpw, opw, ipwT, xpwT, opwT);

    for (int lyr = 0; lyr < DEPTH; lyr++) {
        const float* xin = (lyr == 0) ? x : out;
        float* xout = out;
        const float* alogL = alog + (size_t)lyr * D_INNER * D_STATE;
        const float* dpwL  = dpw + (size_t)lyr * D_INNER * DT_RANK;
        const float* dpbL  = dpb + lyr * D_INNER;

        k_front<<<NCH, 512, 0, stream>>>(
            xin, lnw + lyr * D_MODEL, lnb + lyr * D_MODEL,
            ipwT + (size_t)lyr * 262144,
            cw + (size_t)lyr * D_INNER * D_CONV, cb + lyr * D_INNER,
            xpwT + (size_t)lyr * 24576, dpwL, dpbL, alogL,
            zsB, xcB, dbl, Ssum, sdsum);

        k_comb<<<512, 512, 0, stream>>>(alogL, sdsum, Ssum);

        k_back<<<NCH, 512, 0, stream>>>(
            dbl, xcB, zsB, Ssum, dpwL, dpbL, alogL,
            dpar + lyr * D_INNER,
            opwT + (size_t)lyr * 131072, xin, xout);
    }
}

// Round 7
// 204.024 us; speedup vs baseline: 2.3322x; 1.0041x over previous
//
#include <hip/hip_runtime.h>
#include <hip/hip_bf16.h>
#include <math.h>

// Problem constants
#define D_MODEL 256
#define DEPTH 2
#define D_INNER 512
#define D_STATE 16
#define D_CONV 4
#define DT_RANK 16
#define BATCH 2
#define SEQLEN 2048
#define MROWS (BATCH * SEQLEN)   // 4096

#define LCH 8     // rows per chunk (front)
#define NCH 512   // total chunks
#define CPB 256   // chunks per batch

typedef __attribute__((ext_vector_type(8))) short bf16x8;
typedef __attribute__((ext_vector_type(4))) float f32x4;

__device__ __forceinline__ float silu(float v) {
    return v / (1.0f + __expf(-v));
}

__device__ __forceinline__ ushort f2bf(float f) {
    union { float f; unsigned u; } v; v.f = f;
    unsigned r = v.u + 0x7FFFu + ((v.u >> 16) & 1u);
    return (ushort)(r >> 16);
}

__device__ __forceinline__ float bf2f(ushort u) {
    union { unsigned u; float f; } v; v.u = ((unsigned)u) << 16;
    return v.f;
}

__device__ __forceinline__ float softplus_f(float x) {
    return (x > 20.f) ? x : __logf(1.f + __expf(x));
}

#define XS_STR 260   // f32 stride, 11-row LN tile
#define HS_STR 264   // ushort stride, bf16 LN output (16 rows, 11 valid)
#define XC_STR 520   // ushort stride, xc/yy LDS tiles

// ---------------------------------------------------------------------------
// k_cvt: f32 -> bf16 AND re-layout to MFMA tile-major: per (nt,kt) a 1-KB
// tile [16 r][32 c] so one wave weight-load = one coalesced 1-KB segment.
// ---------------------------------------------------------------------------
__global__ __launch_bounds__(256) void k_cvt(
    const float* __restrict__ ipw, const float* __restrict__ xpw,
    const float* __restrict__ opw, ushort* __restrict__ ipwT,
    ushort* __restrict__ xpwT, ushort* __restrict__ opwT)
{
    size_t tid = (size_t)blockIdx.x * 256 + threadIdx.x;
    {   // ipw: [2][1024 n][256 k] -> per layer [64 nt][8 kt][16 r][32 c]
        int lyr = (int)(tid >> 16), rem = (int)(tid & 65535);
        int n = rem >> 6, k = (rem & 63) * 4;
        float4 v = *(const float4*)(ipw + ((size_t)lyr * 1024 + n) * 256 + k);
        int nt = n >> 4, r = n & 15, kt = k >> 5, c = k & 31;
        ushort4 o = { f2bf(v.x), f2bf(v.y), f2bf(v.z), f2bf(v.w) };
        *(ushort4*)(ipwT + (size_t)lyr * 262144 + (nt * 8 + kt) * 512 + r * 32 + c) = o;
    }
    if (tid < 12288) {   // xpw: [2][48][512] -> per layer [3 nt][16 kt] tiles
        int lyr = (int)(tid / 6144), rem = (int)(tid % 6144);
        int n = rem >> 7, k = (rem & 127) * 4;
        float4 v = *(const float4*)(xpw + ((size_t)lyr * 48 + n) * 512 + k);
        int nt = n >> 4, r = n & 15, kt = k >> 5, c = k & 31;
        ushort4 o = { f2bf(v.x), f2bf(v.y), f2bf(v.z), f2bf(v.w) };
        *(ushort4*)(xpwT + (size_t)lyr * 24576 + (nt * 16 + kt) * 512 + r * 32 + c) = o;
    }
    if (tid < 65536) {   // opw: [2][256][512] -> per layer [16 nt][16 kt]
        int lyr = (int)(tid >> 15), rem = (int)(tid & 32767);
        int n = rem >> 7, k = (rem & 127) * 4;
        float4 v = *(const float4*)(opw + ((size_t)lyr * 256 + n) * 512 + k);
        int nt = n >> 4, r = n & 15, kt = k >> 5, c = k & 31;
        ushort4 o = { f2bf(v.x), f2bf(v.y), f2bf(v.z), f2bf(v.w) };
        *(ushort4*)(opwT + (size_t)lyr * 131072 + (nt * 16 + kt) * 512 + r * 32 + c) = o;
    }
}

// ---------------------------------------------------------------------------
// k_front: 8-row chunk. LN (11 rows, 32 thr/row) + in_proj MFMA (tiled
// weights, explicit 2-deep weight double-buffer, f split 4+4) + conv +
// x_proj + scan_sum. Grid 512 x 512. (Unchanged from R6 — best known.)
// ---------------------------------------------------------------------------
__global__ __launch_bounds__(512, 4) void k_front(
    const float* __restrict__ xin, const float* __restrict__ lnwL,
    const float* __restrict__ lnbL, const ushort* __restrict__ ipwT,
    const float* __restrict__ cwL, const float* __restrict__ cbL,
    const ushort* __restrict__ xpwT, const float* __restrict__ dpwL,
    const float* __restrict__ dpbL, const float* __restrict__ alogL,
    ushort* __restrict__ zsB, ushort* __restrict__ xcB,
    float* __restrict__ dbl, float* __restrict__ Ssum,
    float* __restrict__ sdsum)
{
    const int t = threadIdx.x, bid = blockIdx.x;
    const int lane = t & 63, w = t >> 6, l15 = lane & 15, quad = lane >> 4;
    __shared__ float  xs[11 * XS_STR];     // 11.4 KB
    __shared__ ushort hs[16 * HS_STR];     //  8.4 KB (rows 11-15 garbage)
    __shared__ ushort xi_s[11 * 512];      // 11.3 KB  rows: m0-3 .. m0+7
    __shared__ ushort xc_s[16 * XC_STR];   // 16.6 KB (rows 8-15 garbage)
    __shared__ float  dbl_s[8 * 52];       //  1.7 KB
    int m0 = bid * LCH;

    // ---- stage x rows m0-3 .. m0+7 (clamp row<0) ----
    for (int i = t; i < 11 * 64; i += 512) {
        int r = i >> 6, c = (i & 63) * 4;
        int grow = m0 - 3 + r; if (grow < 0) grow = 0;
        float4 v = *(const float4*)(xin + (size_t)grow * D_MODEL + c);
        *(float4*)&xs[r * XS_STR + c] = v;
    }
    __syncthreads();

    // ---- LayerNorm, 11 rows x 32 threads ----
    if (t < 11 * 32) {
        int r = t >> 5, ci = t & 31;
        float s = 0.f, sq = 0.f;
        #pragma unroll
        for (int k = 0; k < 8; k++) {
            float v = xs[r * XS_STR + ci + 32 * k];
            s += v; sq += v * v;
        }
        #pragma unroll
        for (int off = 1; off < 32; off <<= 1) {
            s  += __shfl_xor(s, off, 32);
            sq += __shfl_xor(sq, off, 32);
        }
        float mu  = s * (1.0f / 256.f);
        float var = sq * (1.0f / 256.f) - mu * mu;
        float rst = rsqrtf(var + 1e-5f);
        #pragma unroll
        for (int k = 0; k < 8; k++) {
            int c = ci + 32 * k;
            float v = (xs[r * XS_STR + c] - mu) * rst * lnwL[c] + lnbL[c];
            hs[r * HS_STR + c] = f2bf(v);
        }
    }
    __syncthreads();

    // ---- in_proj MFMA: f split 4+4, 2-deep weight double-buffer ----
    {
        bf16x8 af[8];
        #pragma unroll
        for (int k8 = 0; k8 < 8; k8++)
            af[k8] = *(const bf16x8*)&hs[l15 * HS_STR + quad * 8 + k8 * 32];
        const ushort* wb = ipwT + (size_t)w * 64 * 512 + l15 * 32 + quad * 8;

        #pragma unroll
        for (int half = 0; half < 2; half++) {
            const ushort* wh = wb + (size_t)half * 4 * 8 * 512;
            f32x4 acc[4];
            #pragma unroll
            for (int f = 0; f < 4; f++) acc[f] = (f32x4){0.f, 0.f, 0.f, 0.f};
            bf16x8 bA[4], bB[4];
            #pragma unroll
            for (int f = 0; f < 4; f++) bA[f] = *(const bf16x8*)(wh + (f * 8) * 512);
            #pragma unroll
            for (int k8 = 0; k8 < 8; k8++) {
                bf16x8* cur = (k8 & 1) ? bB : bA;   // compile-time after unroll
                bf16x8* nxt = (k8 & 1) ? bA : bB;
                if (k8 < 7) {
                    #pragma unroll
                    for (int f = 0; f < 4; f++)
                        nxt[f] = *(const bf16x8*)(wh + (f * 8 + k8 + 1) * 512);
                }
                #pragma unroll
                for (int f = 0; f < 4; f++)
                    acc[f] = __builtin_amdgcn_mfma_f32_16x16x32_bf16(af[k8], cur[f], acc[f], 0, 0, 0);
            }
            #pragma unroll
            for (int f = 0; f < 4; f++) {
                int n = w * 128 + (half * 4 + f) * 16 + l15;
                if (n < 512) {
                    #pragma unroll
                    for (int r2 = 0; r2 < 4; r2++) {
                        int rl = quad * 4 + r2;
                        if (rl < 11) xi_s[rl * 512 + n] = f2bf(acc[f][r2]);
                    }
                } else {
                    #pragma unroll
                    for (int r2 = 0; r2 < 4; r2++) {
                        int rl = quad * 4 + r2;
                        if (rl >= 3 && rl < 11)
                            zsB[(size_t)(m0 + rl - 3) * D_INNER + (n - 512)] =
                                f2bf(silu(acc[f][r2]));
                    }
                }
            }
        }
    }
    __syncthreads();

    // ---- conv(4) + SiLU -> xc_s + xcB. d = t, all 512 threads ----
    {
        float4 cw4 = *(const float4*)(cwL + t * 4);
        float cbv = cbL[t];
        #pragma unroll
        for (int rl = 0; rl < LCH; rl++) {
            int l = (m0 + rl) & (SEQLEN - 1);
            float s = cbv;
            if (l >= 3) s = fmaf(cw4.x, bf2f(xi_s[(rl + 0) * 512 + t]), s);
            if (l >= 2) s = fmaf(cw4.y, bf2f(xi_s[(rl + 1) * 512 + t]), s);
            if (l >= 1) s = fmaf(cw4.z, bf2f(xi_s[(rl + 2) * 512 + t]), s);
            s = fmaf(cw4.w, bf2f(xi_s[(rl + 3) * 512 + t]), s);
            ushort xcv = f2bf(silu(s));
            xc_s[rl * XC_STR + t] = xcv;
            xcB[(size_t)(m0 + rl) * D_INNER + t] = xcv;
        }
    }
    __syncthreads();

    // ---- x_proj MFMA (waves 0..2): prefetch all 16 bw, then MFMA chain ----
    if (w < 3) {
        const ushort* wb = xpwT + (size_t)w * 16 * 512 + l15 * 32 + quad * 8;
        bf16x8 bw[16];
        #pragma unroll
        for (int k8 = 0; k8 < 16; k8++)
            bw[k8] = *(const bf16x8*)(wb + k8 * 512);
        f32x4 acc = (f32x4){0.f, 0.f, 0.f, 0.f};
        #pragma unroll
        for (int k8 = 0; k8 < 16; k8++) {
            bf16x8 af = *(const bf16x8*)&xc_s[l15 * XC_STR + quad * 8 + k8 * 32];
            acc = __builtin_amdgcn_mfma_f32_16x16x32_bf16(af, bw[k8], acc, 0, 0, 0);
        }
        int n = w * 16 + l15;
        #pragma unroll
        for (int r2 = 0; r2 < 4; r2++) {
            int rl = quad * 4 + r2;
            if (rl < LCH) {
                dbl_s[rl * 52 + n] = acc[r2];
                dbl[(size_t)(m0 + rl) * 48 + n] = acc[r2];
            }
        }
    }
    __syncthreads();

    // ---- scan_sum (d = t, all 512 threads), 8 serial steps ----
    {
        float a[16], wdp[16];
        #pragma unroll
        for (int n = 0; n < 16; n++) a[n] = -__expf(alogL[(size_t)t * 16 + n]);
        *(float4*)&wdp[0]  = *(const float4*)(dpwL + (size_t)t * 16 + 0);
        *(float4*)&wdp[4]  = *(const float4*)(dpwL + (size_t)t * 16 + 4);
        *(float4*)&wdp[8]  = *(const float4*)(dpwL + (size_t)t * 16 + 8);
        *(float4*)&wdp[12] = *(const float4*)(dpwL + (size_t)t * 16 + 12);
        float bias = dpbL[t];
        float h[16];
        #pragma unroll
        for (int n = 0; n < 16; n++) h[n] = 0.f;
        float sd = 0.f;
        for (int j = 0; j < LCH; j++) {
            const float* dp = &dbl_s[j * 52];
            float d0 = 0.f, d1 = 0.f;
            #pragma unroll
            for (int r2 = 0; r2 < 8; r2++) {
                d0 = fmaf(dp[r2], wdp[r2], d0);
                d1 = fmaf(dp[8 + r2], wdp[8 + r2], d1);
            }
            float dl = softplus_f(bias + d0 + d1);
            float xv = bf2f(xc_s[j * XC_STR + t]);
            float u = dl * xv;
            sd += dl;
            #pragma unroll
            for (int n = 0; n < 16; n++)
                h[n] = fmaf(__expf(dl * a[n]), h[n], dp[16 + n] * u);
        }
        size_t sbase = (size_t)bid * 16 * D_INNER + t;
        #pragma unroll
        for (int n = 0; n < 16; n++) Ssum[sbase + (size_t)n * D_INNER] = h[n];
        sdsum[(size_t)bid * D_INNER + t] = sd;
    }
}

// ---------------------------------------------------------------------------
// k_comb: two-level exclusive prefix over 512 chunk summaries. Grid 512x512.
// Only EVEN chunks' prefixes are stored (k_back consumes chunk 2*bid only)
// -> halves the write volume.
// ---------------------------------------------------------------------------
__global__ __launch_bounds__(512, 4) void k_comb(
    const float* __restrict__ alogL, const float* __restrict__ sdsum,
    float* __restrict__ Ssum)
{
    const int t = threadIdx.x, bid = blockIdx.x;
    __shared__ float S_l[32][17], sd_l[32][17];
    int ch32 = t & 31, seg = t >> 5;
    int chain = bid * 32 + ch32;
    int d = chain & 511;
    int n = (chain >> 9) & 15;
    int b = chain >> 13;
    float a = -__expf(alogL[(size_t)d * 16 + n]);
    int c0 = b * CPB + seg * 16;

    float s_r[16], sd_r[16];
    float S = 0.f, sdt = 0.f;
    #pragma unroll
    for (int j = 0; j < 16; j++) {
        size_t c = (size_t)(c0 + j);
        float s  = Ssum[(c * 16 + n) * D_INNER + d];
        float sd = sdsum[c * D_INNER + d];
        s_r[j] = s; sd_r[j] = sd;
        S = fmaf(__expf(a * sd), S, s);
        sdt += sd;
    }
    S_l[ch32][seg] = S;
    sd_l[ch32][seg] = sdt;
    __syncthreads();

    if (t < 32) {
        float hi = 0.f;
        #pragma unroll
        for (int g = 0; g < 16; g++) {
            float Sv = S_l[t][g], sdv = sd_l[t][g];
            S_l[t][g] = hi;
            hi = fmaf(__expf(a * sdv), hi, Sv);
        }
    }
    __syncthreads();

    float hi = S_l[ch32][seg];
    #pragma unroll
    for (int j = 0; j < 16; j++) {
        size_t c = (size_t)(c0 + j);
        if (!(j & 1))   // c0 even, so c even iff j even
            Ssum[(c * 16 + n) * D_INNER + d] = hi;
        hi = fmaf(__expf(a * sd_r[j]), hi, s_r[j]);
    }
}

// ---------------------------------------------------------------------------
// k_back: TWO chunks (16 rows) per block. Grid 256 x 512 (1 block/CU).
// Rescan continues through both chunks (prefix of odd chunk = running state),
// reading only the even chunk's Ssum. All 32 xcB/zsB row-loads hoisted and
// batch-issued before the serial chain. out_proj: FULL-density 16-row tiles
// (no garbage rows) -> half the MFMA + half the weight passes per row.
// ---------------------------------------------------------------------------
__global__ __launch_bounds__(512, 2) void k_back(
    const float* __restrict__ dbl, const ushort* __restrict__ xcB,
    const ushort* __restrict__ zsB, const float* __restrict__ Ssum,
    const float* __restrict__ dpwL, const float* __restrict__ dpbL,
    const float* __restrict__ alogL, const float* __restrict__ dparL,
    const ushort* __restrict__ opwT, const float* __restrict__ xin,
    float* __restrict__ xout)
{
    const int t = threadIdx.x, bid = blockIdx.x;
    const int lane = t & 63, w = t >> 6, l15 = lane & 15, quad = lane >> 4;
    __shared__ ushort yy_s[16 * XC_STR];   // 16.6 KB, all 16 rows valid
    __shared__ float  dbl_l[16 * 48];      //  3.0 KB
    int m0 = bid * 16;

    // ---- stage both chunks' dbl rows into LDS ----
    for (int i = t; i < 16 * 48; i += 512) dbl_l[i] = dbl[(size_t)m0 * 48 + i];

    // ---- hoist ALL global inputs for the rescan (batched issue) ----
    ushort xcv[16], zsv[16];
    #pragma unroll
    for (int j = 0; j < 16; j++) {
        size_t rb = (size_t)(m0 + j) * D_INNER + t;
        xcv[j] = xcB[rb];
        zsv[j] = zsB[rb];
    }
    float h[16];
    {
        size_t sbase = ((size_t)(2 * bid) * 16) * D_INNER + t;  // even chunk
        #pragma unroll
        for (int n = 0; n < 16; n++) h[n] = Ssum[sbase + (size_t)n * D_INNER];
    }
    float a[16], wdp[16];
    #pragma unroll
    for (int n = 0; n < 16; n++) a[n] = -__expf(alogL[(size_t)t * 16 + n]);
    *(float4*)&wdp[0]  = *(const float4*)(dpwL + (size_t)t * 16 + 0);
    *(float4*)&wdp[4]  = *(const float4*)(dpwL + (size_t)t * 16 + 4);
    *(float4*)&wdp[8]  = *(const float4*)(dpwL + (size_t)t * 16 + 8);
    *(float4*)&wdp[12] = *(const float4*)(dpwL + (size_t)t * 16 + 12);
    float bias = dpbL[t];
    float Dd = dparL[t];
    __syncthreads();

    // ---- rescan 16 rows, d = t ----
    for (int j = 0; j < 16; j++) {
        const float* dp = &dbl_l[j * 48];
        float d0 = 0.f, d1 = 0.f;
        #pragma unroll
        for (int r2 = 0; r2 < 8; r2++) {
            d0 = fmaf(dp[r2], wdp[r2], d0);
            d1 = fmaf(dp[8 + r2], wdp[8 + r2], d1);
        }
        float dl = softplus_f(bias + d0 + d1);
        float xv = bf2f(xcv[j]);
        float gate = bf2f(zsv[j]);
        float u = dl * xv;
        float y0 = 0.f, y1 = 0.f, y2 = 0.f, y3 = 0.f;
        #pragma unroll
        for (int q = 0; q < 4; q++) {
            h[4 * q + 0] = fmaf(__expf(dl * a[4 * q + 0]), h[4 * q + 0], dp[16 + 4 * q + 0] * u);
            h[4 * q + 1] = fmaf(__expf(dl * a[4 * q + 1]), h[4 * q + 1], dp[16 + 4 * q + 1] * u);
            h[4 * q + 2] = fmaf(__expf(dl * a[4 * q + 2]), h[4 * q + 2], dp[16 + 4 * q + 2] * u);
            h[4 * q + 3] = fmaf(__expf(dl * a[4 * q + 3]), h[4 * q + 3], dp[16 + 4 * q + 3] * u);
            y0 = fmaf(h[4 * q + 0], dp[32 + 4 * q + 0], y0);
            y1 = fmaf(h[4 * q + 1], dp[32 + 4 * q + 1], y1);
            y2 = fmaf(h[4 * q + 2], dp[32 + 4 * q + 2], y2);
            y3 = fmaf(h[4 * q + 3], dp[32 + 4 * q + 3], y3);
        }
        float y = (y0 + y1) + (y2 + y3) + xv * Dd;
        yy_s[j * XC_STR + t] = f2bf(y * gate);
    }
    __syncthreads();

    // ---- out_proj MFMA + residual: full 16-row tiles, 2-deep ping-pong ----
    {
        const ushort* wb = opwT + (size_t)w * 2 * 16 * 512 + l15 * 32 + quad * 8;
        f32x4 acc0 = (f32x4){0.f, 0.f, 0.f, 0.f};
        f32x4 acc1 = (f32x4){0.f, 0.f, 0.f, 0.f};
        bf16x8 bA0 = *(const bf16x8*)(wb + 0 * 512);
        bf16x8 bA1 = *(const bf16x8*)(wb + 16 * 512);
        bf16x8 bB0, bB1;
        #pragma unroll
        for (int k8 = 0; k8 < 16; k8++) {
            if (k8 < 15) {
                if (k8 & 1) { bA0 = *(const bf16x8*)(wb + (k8 + 1) * 512);
                              bA1 = *(const bf16x8*)(wb + (16 + k8 + 1) * 512); }
                else        { bB0 = *(const bf16x8*)(wb + (k8 + 1) * 512);
                              bB1 = *(const bf16x8*)(wb + (16 + k8 + 1) * 512); }
            }
            bf16x8 af = *(const bf16x8*)&yy_s[l15 * XC_STR + quad * 8 + k8 * 32];
            bf16x8 c0 = (k8 & 1) ? bB0 : bA0;
            bf16x8 c1 = (k8 & 1) ? bB1 : bA1;
            acc0 = __builtin_amdgcn_mfma_f32_16x16x32_bf16(af, c0, acc0, 0, 0, 0);
            acc1 = __builtin_amdgcn_mfma_f32_16x16x32_bf16(af, c1, acc1, 0, 0, 0);
        }
        #pragma unroll
        for (int f = 0; f < 2; f++) {
            int n = w * 32 + f * 16 + l15;
            const f32x4& acc = (f == 0) ? acc0 : acc1;
            #pragma unroll
            for (int r2 = 0; r2 < 4; r2++) {
                int row = m0 + quad * 4 + r2;   // all 16 rows valid
                xout[(size_t)row * D_MODEL + n] =
                    acc[r2] + xin[(size_t)row * D_MODEL + n];
            }
        }
    }
}

// ---------------------------------------------------------------------------
// Launch. Inter-layer activation routed through d_out.
// ---------------------------------------------------------------------------
extern "C" void kernel_launch(void* const* d_in, const int* in_sizes, int n_in,
                              void* d_out, int out_size, void* d_ws, size_t ws_size,
                              hipStream_t stream)
{
    const float* x    = (const float*)d_in[0];
    const float* lnw  = (const float*)d_in[1];
    const float* lnb  = (const float*)d_in[2];
    const float* ipw  = (const float*)d_in[3];
    const float* cw   = (const float*)d_in[4];
    const float* cb   = (const float*)d_in[5];
    const float* xpw  = (const float*)d_in[6];
    const float* dpw  = (const float*)d_in[7];
    const float* dpb  = (const float*)d_in[8];
    const float* alog = (const float*)d_in[9];
    const float* dpar = (const float*)d_in[10];
    const float* opw  = (const float*)d_in[11];
    float* out = (float*)d_out;

    char* p = (char*)d_ws;
    auto alloc = [&](size_t bytes) { char* r = p; p += (bytes + 255) & ~(size_t)255; return r; };
    ushort* zsB   = (ushort*)alloc((size_t)MROWS * D_INNER * 2);
    ushort* xcB   = (ushort*)alloc((size_t)MROWS * D_INNER * 2);
    float*  dbl   = (float*)alloc((size_t)MROWS * 48 * 4);
    float*  Ssum  = (float*)alloc((size_t)NCH * 16 * D_INNER * 4);
    float*  sdsum = (float*)alloc((size_t)NCH * D_INNER * 4);
    ushort* ipwT  = (ushort*)alloc((size_t)DEPTH * 262144 * 2);
    ushort* xpwT  = (ushort*)alloc((size_t)DEPTH * 24576 * 2);
    ushort* opwT  = (ushort*)alloc((size_t)DEPTH * 131072 * 2);

    k_cvt<<<512, 256, 0, stream>>>(ipw, xpw, opw, ipwT, xpwT, opwT);

    for (int lyr = 0; lyr < DEPTH; lyr++) {
        const float* xin = (lyr == 0) ? x : out;
        float* xout = out;
        const float* alogL = alog + (size_t)lyr * D_INNER * D_STATE;
        const float* dpwL  = dpw + (size_t)lyr * D_INNER * DT_RANK;
        const float* dpbL  = dpb + lyr * D_INNER;

        k_front<<<NCH, 512, 0, stream>>>(
            xin, lnw + lyr * D_MODEL, lnb + lyr * D_MODEL,
            ipwT + (size_t)lyr * 262144,
            cw + (size_t)lyr * D_INNER * D_CONV, cb + lyr * D_INNER,
            xpwT + (size_t)lyr * 24576, dpwL, dpbL, alogL,
            zsB, xcB, dbl, Ssum, sdsum);

        k_comb<<<512, 512, 0, stream>>>(alogL, sdsum, Ssum);

        k_back<<<NCH / 2, 512, 0, stream>>>(
            dbl, xcB, zsB, Ssum, dpwL, dpbL, alogL,
            dpar + lyr * D_INNER,
            opwT + (size_t)lyr * 131072, xin, xout);
    }
}

// Round 9
// 199.967 us; speedup vs baseline: 2.3795x; 1.0203x over previous
//
#include <hip/hip_runtime.h>
#include <hip/hip_bf16.h>
#include <math.h>

// Problem constants
#define D_MODEL 256
#define DEPTH 2
#define D_INNER 512
#define D_STATE 16
#define D_CONV 4
#define DT_RANK 16
#define BATCH 2
#define SEQLEN 2048
#define MROWS (BATCH * SEQLEN)   // 4096

#define LCH 8     // rows per chunk (front)
#define NCH 512   // total chunks
#define CPB 256   // chunks per batch

typedef __attribute__((ext_vector_type(8))) short bf16x8;
typedef __attribute__((ext_vector_type(4))) float f32x4;

__device__ __forceinline__ float silu(float v) {
    return v / (1.0f + __expf(-v));
}

__device__ __forceinline__ ushort f2bf(float f) {
    union { float f; unsigned u; } v; v.f = f;
    unsigned r = v.u + 0x7FFFu + ((v.u >> 16) & 1u);
    return (ushort)(r >> 16);
}

__device__ __forceinline__ float bf2f(ushort u) {
    union { unsigned u; float f; } v; v.u = ((unsigned)u) << 16;
    return v.f;
}

__device__ __forceinline__ float softplus_f(float x) {
    return (x > 20.f) ? x : __logf(1.f + __expf(x));
}

#define XS_STR 260   // f32 stride, 11-row LN tile
#define HS_STR 264   // ushort stride, bf16 LN output (16 rows, 11 valid)
#define XC_STR 520   // ushort stride, xc/yy LDS tiles

// ---------------------------------------------------------------------------
// k_cvt: f32 -> bf16 AND re-layout to MFMA tile-major: per (nt,kt) a 1-KB
// tile [16 r][32 c] so one wave weight-load = one coalesced 1-KB segment.
// ---------------------------------------------------------------------------
__global__ __launch_bounds__(256) void k_cvt(
    const float* __restrict__ ipw, const float* __restrict__ xpw,
    const float* __restrict__ opw, ushort* __restrict__ ipwT,
    ushort* __restrict__ xpwT, ushort* __restrict__ opwT)
{
    size_t tid = (size_t)blockIdx.x * 256 + threadIdx.x;
    {   // ipw: [2][1024 n][256 k] -> per layer [64 nt][8 kt][16 r][32 c]
        int lyr = (int)(tid >> 16), rem = (int)(tid & 65535);
        int n = rem >> 6, k = (rem & 63) * 4;
        float4 v = *(const float4*)(ipw + ((size_t)lyr * 1024 + n) * 256 + k);
        int nt = n >> 4, r = n & 15, kt = k >> 5, c = k & 31;
        ushort4 o = { f2bf(v.x), f2bf(v.y), f2bf(v.z), f2bf(v.w) };
        *(ushort4*)(ipwT + (size_t)lyr * 262144 + (nt * 8 + kt) * 512 + r * 32 + c) = o;
    }
    if (tid < 12288) {   // xpw: [2][48][512] -> per layer [3 nt][16 kt] tiles
        int lyr = (int)(tid / 6144), rem = (int)(tid % 6144);
        int n = rem >> 7, k = (rem & 127) * 4;
        float4 v = *(const float4*)(xpw + ((size_t)lyr * 48 + n) * 512 + k);
        int nt = n >> 4, r = n & 15, kt = k >> 5, c = k & 31;
        ushort4 o = { f2bf(v.x), f2bf(v.y), f2bf(v.z), f2bf(v.w) };
        *(ushort4*)(xpwT + (size_t)lyr * 24576 + (nt * 16 + kt) * 512 + r * 32 + c) = o;
    }
    if (tid < 65536) {   // opw: [2][256][512] -> per layer [16 nt][16 kt]
        int lyr = (int)(tid >> 15), rem = (int)(tid & 32767);
        int n = rem >> 7, k = (rem & 127) * 4;
        float4 v = *(const float4*)(opw + ((size_t)lyr * 256 + n) * 512 + k);
        int nt = n >> 4, r = n & 15, kt = k >> 5, c = k & 31;
        ushort4 o = { f2bf(v.x), f2bf(v.y), f2bf(v.z), f2bf(v.w) };
        *(ushort4*)(opwT + (size_t)lyr * 131072 + (nt * 16 + kt) * 512 + r * 32 + c) = o;
    }
}

// ---------------------------------------------------------------------------
// k_front: 8-row chunk, 5 phases / 4 barriers.
//   stage (x + conv weights) | LN | in_proj MFMA + IN-REGISTER conv via
//   cross-quad shfl (xi never touches LDS) | x_proj | scan_sum.
// Scan params hoisted before x_proj so the scan phase starts latency-free.
// Grid 512 x 512.
// ---------------------------------------------------------------------------
__global__ __launch_bounds__(512, 4) void k_front(
    const float* __restrict__ xin, const float* __restrict__ lnwL,
    const float* __restrict__ lnbL, const ushort* __restrict__ ipwT,
    const float* __restrict__ cwL, const float* __restrict__ cbL,
    const ushort* __restrict__ xpwT, const float* __restrict__ dpwL,
    const float* __restrict__ dpbL, const float* __restrict__ alogL,
    ushort* __restrict__ zsB, ushort* __restrict__ xcB,
    float* __restrict__ dbl, float* __restrict__ Ssum,
    float* __restrict__ sdsum)
{
    const int t = threadIdx.x, bid = blockIdx.x;
    const int lane = t & 63, w = t >> 6, l15 = lane & 15, quad = lane >> 4;
    __shared__ float  xs[11 * XS_STR];     // 11.4 KB
    __shared__ ushort hs[16 * HS_STR];     //  8.4 KB (rows 11-15 garbage)
    __shared__ ushort xc_s[16 * XC_STR];   // 16.6 KB (rows 8-15 garbage)
    __shared__ float  dbl_s[8 * 52];       //  1.7 KB
    __shared__ float4 cw_s[512];           //  8.0 KB
    __shared__ float  cb_s[512];           //  2.0 KB
    int m0 = bid * LCH;

    // ---- stage x rows m0-3 .. m0+7 (clamp row<0) + conv weights ----
    cw_s[t] = *(const float4*)(cwL + t * 4);
    cb_s[t] = cbL[t];
    for (int i = t; i < 11 * 64; i += 512) {
        int r = i >> 6, c = (i & 63) * 4;
        int grow = m0 - 3 + r; if (grow < 0) grow = 0;
        float4 v = *(const float4*)(xin + (size_t)grow * D_MODEL + c);
        *(float4*)&xs[r * XS_STR + c] = v;
    }
    __syncthreads();

    // ---- LayerNorm, 11 rows x 32 threads ----
    if (t < 11 * 32) {
        int r = t >> 5, ci = t & 31;
        float s = 0.f, sq = 0.f;
        #pragma unroll
        for (int k = 0; k < 8; k++) {
            float v = xs[r * XS_STR + ci + 32 * k];
            s += v; sq += v * v;
        }
        #pragma unroll
        for (int off = 1; off < 32; off <<= 1) {
            s  += __shfl_xor(s, off, 32);
            sq += __shfl_xor(sq, off, 32);
        }
        float mu  = s * (1.0f / 256.f);
        float var = sq * (1.0f / 256.f) - mu * mu;
        float rst = rsqrtf(var + 1e-5f);
        #pragma unroll
        for (int k = 0; k < 8; k++) {
            int c = ci + 32 * k;
            float v = (xs[r * XS_STR + c] - mu) * rst * lnwL[c] + lnbL[c];
            hs[r * HS_STR + c] = f2bf(v);
        }
    }
    __syncthreads();

    // ---- in_proj MFMA (f split 4+4, 2-deep weight dbuf) + fused conv ----
    {
        bf16x8 af[8];
        #pragma unroll
        for (int k8 = 0; k8 < 8; k8++)
            af[k8] = *(const bf16x8*)&hs[l15 * HS_STR + quad * 8 + k8 * 32];
        const ushort* wb = ipwT + (size_t)w * 64 * 512 + l15 * 32 + quad * 8;

        #pragma unroll
        for (int half = 0; half < 2; half++) {
            const ushort* wh = wb + (size_t)half * 4 * 8 * 512;
            f32x4 acc[4];
            #pragma unroll
            for (int f = 0; f < 4; f++) acc[f] = (f32x4){0.f, 0.f, 0.f, 0.f};
            bf16x8 bA[4], bB[4];
            #pragma unroll
            for (int f = 0; f < 4; f++) bA[f] = *(const bf16x8*)(wh + (f * 8) * 512);
            #pragma unroll
            for (int k8 = 0; k8 < 8; k8++) {
                bf16x8* cur = (k8 & 1) ? bB : bA;
                bf16x8* nxt = (k8 & 1) ? bA : bB;
                if (k8 < 7) {
                    #pragma unroll
                    for (int f = 0; f < 4; f++)
                        nxt[f] = *(const bf16x8*)(wh + (f * 8 + k8 + 1) * 512);
                }
                #pragma unroll
                for (int f = 0; f < 4; f++)
                    acc[f] = __builtin_amdgcn_mfma_f32_16x16x32_bf16(af[k8], cur[f], acc[f], 0, 0, 0);
            }

            if (w < 4) {
                // fused conv: xi rows live in acc across quads.
                // Row R=quad*4+r2 (R=0..15, valid xi rows 0..10). conv out row
                // j=R-3 (valid 0..7) needs xi[R-3..R]; cross-quad values via
                // shfl_up(16). Emit per r2 with compile-time tap selection.
                #pragma unroll
                for (int f = 0; f < 4; f++) {
                    int n = w * 128 + (half * 4 + f) * 16 + l15;
                    float x0 = acc[f][0], x1 = acc[f][1], x2 = acc[f][2], x3 = acc[f][3];
                    float p1 = __shfl_up(x1, 16);
                    float p2 = __shfl_up(x2, 16);
                    float p3 = __shfl_up(x3, 16);
                    float4 cwv = cw_s[n];
                    float cbv = cb_s[n];
                    int jb = quad * 4 - 3;
                    #define EMIT(JOFF, T0, T1, T2, T3)                          \
                    {   int j = jb + (JOFF);                                    \
                        if (j >= 0 && j < 8) {                                  \
                            int l = (m0 + j) & (SEQLEN - 1);                    \
                            float s = cbv;                                      \
                            if (l >= 3) s = fmaf(cwv.x, (T0), s);               \
                            if (l >= 2) s = fmaf(cwv.y, (T1), s);               \
                            if (l >= 1) s = fmaf(cwv.z, (T2), s);               \
                            s = fmaf(cwv.w, (T3), s);                           \
                            ushort xv = f2bf(silu(s));                          \
                            xc_s[j * XC_STR + n] = xv;                          \
                            xcB[(size_t)(m0 + j) * D_INNER + n] = xv;           \
                        }                                                       \
                    }
                    EMIT(0, p1, p2, p3, x0)
                    EMIT(1, p2, p3, x0, x1)
                    EMIT(2, p3, x0, x1, x2)
                    EMIT(3, x0, x1, x2, x3)
                    #undef EMIT
                }
            } else {
                // z path: n >= 512, valid rows rl 3..10 -> global m0..m0+7
                #pragma unroll
                for (int f = 0; f < 4; f++) {
                    int n = w * 128 + (half * 4 + f) * 16 + l15;
                    #pragma unroll
                    for (int r2 = 0; r2 < 4; r2++) {
                        int rl = quad * 4 + r2;
                        if (rl >= 3 && rl < 11)
                            zsB[(size_t)(m0 + rl - 3) * D_INNER + (n - 512)] =
                                f2bf(silu(acc[f][r2]));
                    }
                }
            }
        }
    }

    // ---- hoist scan params + compute a[] (overlaps x_proj phase) ----
    float a[16], wdp[16];
    {
        float al[16];
        *(float4*)&al[0]   = *(const float4*)(alogL + (size_t)t * 16 + 0);
        *(float4*)&al[4]   = *(const float4*)(alogL + (size_t)t * 16 + 4);
        *(float4*)&al[8]   = *(const float4*)(alogL + (size_t)t * 16 + 8);
        *(float4*)&al[12]  = *(const float4*)(alogL + (size_t)t * 16 + 12);
        #pragma unroll
        for (int n = 0; n < 16; n++) a[n] = -__expf(al[n]);
    }
    *(float4*)&wdp[0]  = *(const float4*)(dpwL + (size_t)t * 16 + 0);
    *(float4*)&wdp[4]  = *(const float4*)(dpwL + (size_t)t * 16 + 4);
    *(float4*)&wdp[8]  = *(const float4*)(dpwL + (size_t)t * 16 + 8);
    *(float4*)&wdp[12] = *(const float4*)(dpwL + (size_t)t * 16 + 12);
    float bias = dpbL[t];
    __syncthreads();

    // ---- x_proj MFMA (waves 0..2): prefetch all 16 bw, then MFMA chain ----
    if (w < 3) {
        const ushort* wb = xpwT + (size_t)w * 16 * 512 + l15 * 32 + quad * 8;
        bf16x8 bw[16];
        #pragma unroll
        for (int k8 = 0; k8 < 16; k8++)
            bw[k8] = *(const bf16x8*)(wb + k8 * 512);
        f32x4 acc = (f32x4){0.f, 0.f, 0.f, 0.f};
        #pragma unroll
        for (int k8 = 0; k8 < 16; k8++) {
            bf16x8 af = *(const bf16x8*)&xc_s[l15 * XC_STR + quad * 8 + k8 * 32];
            acc = __builtin_amdgcn_mfma_f32_16x16x32_bf16(af, bw[k8], acc, 0, 0, 0);
        }
        int n = w * 16 + l15;
        #pragma unroll
        for (int r2 = 0; r2 < 4; r2++) {
            int rl = quad * 4 + r2;
            if (rl < LCH) {
                dbl_s[rl * 52 + n] = acc[r2];
                dbl[(size_t)(m0 + rl) * 48 + n] = acc[r2];
            }
        }
    }
    __syncthreads();

    // ---- scan_sum (d = t, all 512 threads), 8 serial steps ----
    {
        float h[16];
        #pragma unroll
        for (int n = 0; n < 16; n++) h[n] = 0.f;
        float sd = 0.f;
        for (int j = 0; j < LCH; j++) {
            const float* dp = &dbl_s[j * 52];
            float d0 = 0.f, d1 = 0.f;
            #pragma unroll
            for (int r2 = 0; r2 < 8; r2++) {
                d0 = fmaf(dp[r2], wdp[r2], d0);
                d1 = fmaf(dp[8 + r2], wdp[8 + r2], d1);
            }
            float dl = softplus_f(bias + d0 + d1);
            float xv = bf2f(xc_s[j * XC_STR + t]);
            float u = dl * xv;
            sd += dl;
            #pragma unroll
            for (int n = 0; n < 16; n++)
                h[n] = fmaf(__expf(dl * a[n]), h[n], dp[16 + n] * u);
        }
        size_t sbase = (size_t)bid * 16 * D_INNER + t;
        #pragma unroll
        for (int n = 0; n < 16; n++) Ssum[sbase + (size_t)n * D_INNER] = h[n];
        sdsum[(size_t)bid * D_INNER + t] = sd;
    }
}

// ---------------------------------------------------------------------------
// k_comb: two-level exclusive prefix over 512 chunk summaries. Grid 512x512.
// Only EVEN chunks' prefixes are stored (k_back consumes chunk 2*bid only).
// ---------------------------------------------------------------------------
__global__ __launch_bounds__(512, 4) void k_comb(
    const float* __restrict__ alogL, const float* __restrict__ sdsum,
    float* __restrict__ Ssum)
{
    const int t = threadIdx.x, bid = blockIdx.x;
    __shared__ float S_l[32][17], sd_l[32][17];
    int ch32 = t & 31, seg = t >> 5;
    int chain = bid * 32 + ch32;
    int d = chain & 511;
    int n = (chain >> 9) & 15;
    int b = chain >> 13;
    float a = -__expf(alogL[(size_t)d * 16 + n]);
    int c0 = b * CPB + seg * 16;

    float s_r[16], sd_r[16];
    float S = 0.f, sdt = 0.f;
    #pragma unroll
    for (int j = 0; j < 16; j++) {
        size_t c = (size_t)(c0 + j);
        float s  = Ssum[(c * 16 + n) * D_INNER + d];
        float sd = sdsum[c * D_INNER + d];
        s_r[j] = s; sd_r[j] = sd;
        S = fmaf(__expf(a * sd), S, s);
        sdt += sd;
    }
    S_l[ch32][seg] = S;
    sd_l[ch32][seg] = sdt;
    __syncthreads();

    if (t < 32) {
        float hi = 0.f;
        #pragma unroll
        for (int g = 0; g < 16; g++) {
            float Sv = S_l[t][g], sdv = sd_l[t][g];
            S_l[t][g] = hi;
            hi = fmaf(__expf(a * sdv), hi, Sv);
        }
    }
    __syncthreads();

    float hi = S_l[ch32][seg];
    #pragma unroll
    for (int j = 0; j < 16; j++) {
        size_t c = (size_t)(c0 + j);
        if (!(j & 1))   // c0 even, so c even iff j even
            Ssum[(c * 16 + n) * D_INNER + d] = hi;
        hi = fmaf(__expf(a * sd_r[j]), hi, s_r[j]);
    }
}

// ---------------------------------------------------------------------------
// k_back: TWO chunks (16 rows) per block. Grid 256 x 512.
// Rescan continues through both chunks; only even chunk's Ssum read.
// All loads hoisted/batched; out_proj full-density 16-row tiles.
// ---------------------------------------------------------------------------
__global__ __launch_bounds__(512, 2) void k_back(
    const float* __restrict__ dbl, const ushort* __restrict__ xcB,
    const ushort* __restrict__ zsB, const float* __restrict__ Ssum,
    const float* __restrict__ dpwL, const float* __restrict__ dpbL,
    const float* __restrict__ alogL, const float* __restrict__ dparL,
    const ushort* __restrict__ opwT, const float* __restrict__ xin,
    float* __restrict__ xout)
{
    const int t = threadIdx.x, bid = blockIdx.x;
    const int lane = t & 63, w = t >> 6, l15 = lane & 15, quad = lane >> 4;
    __shared__ ushort yy_s[16 * XC_STR];   // 16.6 KB, all 16 rows valid
    __shared__ float  dbl_l[16 * 48];      //  3.0 KB
    int m0 = bid * 16;

    // ---- stage both chunks' dbl rows into LDS ----
    for (int i = t; i < 16 * 48; i += 512) dbl_l[i] = dbl[(size_t)m0 * 48 + i];

    // ---- hoist ALL global inputs for the rescan (batched issue) ----
    ushort xcv[16], zsv[16];
    #pragma unroll
    for (int j = 0; j < 16; j++) {
        size_t rb = (size_t)(m0 + j) * D_INNER + t;
        xcv[j] = xcB[rb];
        zsv[j] = zsB[rb];
    }
    float h[16];
    {
        size_t sbase = ((size_t)(2 * bid) * 16) * D_INNER + t;  // even chunk
        #pragma unroll
        for (int n = 0; n < 16; n++) h[n] = Ssum[sbase + (size_t)n * D_INNER];
    }
    float a[16], wdp[16];
    {
        float al[16];
        *(float4*)&al[0]  = *(const float4*)(alogL + (size_t)t * 16 + 0);
        *(float4*)&al[4]  = *(const float4*)(alogL + (size_t)t * 16 + 4);
        *(float4*)&al[8]  = *(const float4*)(alogL + (size_t)t * 16 + 8);
        *(float4*)&al[12] = *(const float4*)(alogL + (size_t)t * 16 + 12);
        #pragma unroll
        for (int n = 0; n < 16; n++) a[n] = -__expf(al[n]);
    }
    *(float4*)&wdp[0]  = *(const float4*)(dpwL + (size_t)t * 16 + 0);
    *(float4*)&wdp[4]  = *(const float4*)(dpwL + (size_t)t * 16 + 4);
    *(float4*)&wdp[8]  = *(const float4*)(dpwL + (size_t)t * 16 + 8);
    *(float4*)&wdp[12] = *(const float4*)(dpwL + (size_t)t * 16 + 12);
    float bias = dpbL[t];
    float Dd = dparL[t];
    __syncthreads();

    // ---- rescan 16 rows, d = t ----
    for (int j = 0; j < 16; j++) {
        const float* dp = &dbl_l[j * 48];
        float d0 = 0.f, d1 = 0.f;
        #pragma unroll
        for (int r2 = 0; r2 < 8; r2++) {
            d0 = fmaf(dp[r2], wdp[r2], d0);
            d1 = fmaf(dp[8 + r2], wdp[8 + r2], d1);
        }
        float dl = softplus_f(bias + d0 + d1);
        float xv = bf2f(xcv[j]);
        float gate = bf2f(zsv[j]);
        float u = dl * xv;
        float y0 = 0.f, y1 = 0.f, y2 = 0.f, y3 = 0.f;
        #pragma unroll
        for (int q = 0; q < 4; q++) {
            h[4 * q + 0] = fmaf(__expf(dl * a[4 * q + 0]), h[4 * q + 0], dp[16 + 4 * q + 0] * u);
            h[4 * q + 1] = fmaf(__expf(dl * a[4 * q + 1]), h[4 * q + 1], dp[16 + 4 * q + 1] * u);
            h[4 * q + 2] = fmaf(__expf(dl * a[4 * q + 2]), h[4 * q + 2], dp[16 + 4 * q + 2] * u);
            h[4 * q + 3] = fmaf(__expf(dl * a[4 * q + 3]), h[4 * q + 3], dp[16 + 4 * q + 3] * u);
            y0 = fmaf(h[4 * q + 0], dp[32 + 4 * q + 0], y0);
            y1 = fmaf(h[4 * q + 1], dp[32 + 4 * q + 1], y1);
            y2 = fmaf(h[4 * q + 2], dp[32 + 4 * q + 2], y2);
            y3 = fmaf(h[4 * q + 3], dp[32 + 4 * q + 3], y3);
        }
        float y = (y0 + y1) + (y2 + y3) + xv * Dd;
        yy_s[j * XC_STR + t] = f2bf(y * gate);
    }
    __syncthreads();

    // ---- out_proj MFMA + residual: full 16-row tiles, 2-deep ping-pong ----
    {
        const ushort* wb = opwT + (size_t)w * 2 * 16 * 512 + l15 * 32 + quad * 8;
        f32x4 acc0 = (f32x4){0.f, 0.f, 0.f, 0.f};
        f32x4 acc1 = (f32x4){0.f, 0.f, 0.f, 0.f};
        bf16x8 bA0 = *(const bf16x8*)(wb + 0 * 512);
        bf16x8 bA1 = *(const bf16x8*)(wb + 16 * 512);
        bf16x8 bB0, bB1;
        #pragma unroll
        for (int k8 = 0; k8 < 16; k8++) {
            if (k8 < 15) {
                if (k8 & 1) { bA0 = *(const bf16x8*)(wb + (k8 + 1) * 512);
                              bA1 = *(const bf16x8*)(wb + (16 + k8 + 1) * 512); }
                else        { bB0 = *(const bf16x8*)(wb + (k8 + 1) * 512);
                              bB1 = *(const bf16x8*)(wb + (16 + k8 + 1) * 512); }
            }
            bf16x8 af = *(const bf16x8*)&yy_s[l15 * XC_STR + quad * 8 + k8 * 32];
            bf16x8 c0 = (k8 & 1) ? bB0 : bA0;
            bf16x8 c1 = (k8 & 1) ? bB1 : bA1;
            acc0 = __builtin_amdgcn_mfma_f32_16x16x32_bf16(af, c0, acc0, 0, 0, 0);
            acc1 = __builtin_amdgcn_mfma_f32_16x16x32_bf16(af, c1, acc1, 0, 0, 0);
        }
        #pragma unroll
        for (int f = 0; f < 2; f++) {
            int n = w * 32 + f * 16 + l15;
            const f32x4& acc = (f == 0) ? acc0 : acc1;
            #pragma unroll
            for (int r2 = 0; r2 < 4; r2++) {
                int row = m0 + quad * 4 + r2;
                xout[(size_t)row * D_MODEL + n] =
                    acc[r2] + xin[(size_t)row * D_MODEL + n];
            }
        }
    }
}

// ---------------------------------------------------------------------------
// Launch. Inter-layer activation routed through d_out.
// ---------------------------------------------------------------------------
extern "C" void kernel_launch(void* const* d_in, const int* in_sizes, int n_in,
                              void* d_out, int out_size, void* d_ws, size_t ws_size,
                              hipStream_t stream)
{
    const float* x    = (const float*)d_in[0];
    const float* lnw  = (const float*)d_in[1];
    const float* lnb  = (const float*)d_in[2];
    const float* ipw  = (const float*)d_in[3];
    const float* cw   = (const float*)d_in[4];
    const float* cb   = (const float*)d_in[5];
    const float* xpw  = (const float*)d_in[6];
    const float* dpw  = (const float*)d_in[7];
    const float* dpb  = (const float*)d_in[8];
    const float* alog = (const float*)d_in[9];
    const float* dpar = (const float*)d_in[10];
    const float* opw  = (const float*)d_in[11];
    float* out = (float*)d_out;

    char* p = (char*)d_ws;
    auto alloc = [&](size_t bytes) { char* r = p; p += (bytes + 255) & ~(size_t)255; return r; };
    ushort* zsB   = (ushort*)alloc((size_t)MROWS * D_INNER * 2);
    ushort* xcB   = (ushort*)alloc((size_t)MROWS * D_INNER * 2);
    float*  dbl   = (float*)alloc((size_t)MROWS * 48 * 4);
    float*  Ssum  = (float*)alloc((size_t)NCH * 16 * D_INNER * 4);
    float*  sdsum = (float*)alloc((size_t)NCH * D_INNER * 4);
    ushort* ipwT  = (ushort*)alloc((size_t)DEPTH * 262144 * 2);
    ushort* xpwT  = (ushort*)alloc((size_t)DEPTH * 24576 * 2);
    ushort* opwT  = (ushort*)alloc((size_t)DEPTH * 131072 * 2);

    k_cvt<<<512, 256, 0, stream>>>(ipw, xpw, opw, ipwT, xpwT, opwT);

    for (int lyr = 0; lyr < DEPTH; lyr++) {
        const float* xin = (lyr == 0) ? x : out;
        float* xout = out;
        const float* alogL = alog + (size_t)lyr * D_INNER * D_STATE;
        const float* dpwL  = dpw + (size_t)lyr * D_INNER * DT_RANK;
        const float* dpbL  = dpb + lyr * D_INNER;

        k_front<<<NCH, 512, 0, stream>>>(
            xin, lnw + lyr * D_MODEL, lnb + lyr * D_MODEL,
            ipwT + (size_t)lyr * 262144,
            cw + (size_t)lyr * D_INNER * D_CONV, cb + lyr * D_INNER,
            xpwT + (size_t)lyr * 24576, dpwL, dpbL, alogL,
            zsB, xcB, dbl, Ssum, sdsum);

        k_comb<<<512, 512, 0, stream>>>(alogL, sdsum, Ssum);

        k_back<<<NCH / 2, 512, 0, stream>>>(
            dbl, xcB, zsB, Ssum, dpwL, dpbL, alogL,
            dpar + lyr * D_INNER,
            opwT + (size_t)lyr * 131072, xin, xout);
    }
}